// Round 1
// baseline (1290.660 us; speedup 1.0000x reference)
//
#include <hip/hip_runtime.h>
#include <math.h>

#define NN 12000
#define EE 384000
#define FF 128
#define NOUT 40
#define BJ_ITERS 25

// ---------------- degree counting ----------------
__global__ __launch_bounds__(256) void build_deg(const int* __restrict__ ei,
    float* __restrict__ degf, int* __restrict__ cnt) {
  int e = blockIdx.x * 256 + threadIdx.x;
  if (e >= EE) return;
  atomicAdd(&degf[ei[e]], 1.0f);        // out-degree of r (rowsum of adj)
  atomicAdd(&cnt[ei[EE + e]], 1);       // in-degree of c (CSR by destination)
}

// ---------------- exclusive scan over cnt[NN] -> rowstart[NN+1] ----------------
__global__ __launch_bounds__(1024) void scan_kernel(const int* __restrict__ cnt,
    int* __restrict__ rowstart) {
  __shared__ int sums[1024];
  int tid = threadIdx.x;
  const int CH = 12;                    // 12*1024 = 12288 >= NN
  int base = tid * CH;
  int local[CH];
  int s = 0;
  #pragma unroll
  for (int m = 0; m < CH; m++) {
    int idx = base + m;
    int v = (idx < NN) ? cnt[idx] : 0;
    local[m] = s;
    s += v;
  }
  sums[tid] = s;
  __syncthreads();
  for (int off = 1; off < 1024; off <<= 1) {
    int v = (tid >= off) ? sums[tid - off] : 0;
    __syncthreads();
    sums[tid] += v;
    __syncthreads();
  }
  int excl = (tid > 0) ? sums[tid - 1] : 0;
  #pragma unroll
  for (int m = 0; m < CH; m++) {
    int idx = base + m;
    if (idx < NN) rowstart[idx] = excl + local[m];
  }
  if (tid == 1023) rowstart[NN] = sums[1023];
}

// ---------------- scatter edges into CSR lists ----------------
__global__ __launch_bounds__(256) void scatter_edges(const int* __restrict__ ei,
    const int* __restrict__ rowstart, int* __restrict__ fill, int* __restrict__ srcl) {
  int e = blockIdx.x * 256 + threadIdx.x;
  if (e >= EE) return;
  int r = ei[e], c = ei[EE + e];
  int pos = rowstart[c] + atomicAdd(&fill[c], 1);
  srcl[pos] = r;
}

__global__ __launch_bounds__(256) void dinv_kernel(const float* __restrict__ degf,
    float* __restrict__ dinv) {
  int i = blockIdx.x * 256 + threadIdx.x;
  if (i >= NN) return;
  float dv = degf[i];
  dinv[i] = (dv > 0.0f) ? (1.0f / sqrtf(dv)) : 0.0f;
}

// ---------------- Bjorck orthonormalization ----------------
// One workgroup per weight. w kept in global ping-pong buffers; M/P in LDS.
// w_new = w * P,  P = 1.875 I - 1.25 M + 0.375 M^2,  M = w^T w  (M exactly symmetric)
__global__ __launch_bounds__(512) void bjorck_kernel(const float* __restrict__ W1,
    const float* __restrict__ W2, float* __restrict__ wb, float* __restrict__ wf) {
  __shared__ float sM[FF * FF];   // 64 KiB exactly
  const int L = blockIdx.x;
  const float* Wsrc = (L == 0) ? W1 : W2;
  float* buf0 = wb + L * 2 * FF * FF;
  float* buf1 = buf0 + FF * FF;
  float* wfin = wf + L * FF * FF;
  int tid = threadIdx.x;

  // ---- scaling = sqrt(max abs row-sum * max abs col-sum) ----
  if (tid < 128) {
    float s = 0.0f;
    for (int j = 0; j < FF; j++) s += fabsf(Wsrc[tid * FF + j]);
    sM[tid] = s;
  } else if (tid < 256) {
    int i = tid - 128;
    float s = 0.0f;
    for (int j = 0; j < FF; j++) s += fabsf(Wsrc[j * FF + i]);
    sM[tid] = s;
  }
  __syncthreads();
  if (tid == 0) {
    float rm = 0.0f, cm = 0.0f;
    for (int i = 0; i < 128; i++) { rm = fmaxf(rm, sM[i]); cm = fmaxf(cm, sM[128 + i]); }
    sM[256] = 1.0f / sqrtf(rm * cm);
  }
  __syncthreads();
  float inv_s = sM[256];

  // ---- w0 = W^T * inv_s  ->  buf0 ----
  for (int m = 0; m < 32; m++) {
    int idx = tid + m * 512;
    int i = idx >> 7, j = idx & 127;
    buf0[idx] = Wsrc[j * FF + i] * inv_s;
  }
  __syncthreads();

  float* cur = buf0;
  float* nxt = buf1;
  const int tr = tid >> 4;        // 0..31
  const int tc = tid & 15;        // 0..15
  const int a0 = tr * 4;          // row tile
  const int b0 = tc * 8;          // col tile

  for (int it = 0; it < BJ_ITERS; it++) {
    // stage cur -> sM
    {
      const float4* cv = (const float4*)cur;
      float4* sv = (float4*)sM;
      #pragma unroll
      for (int m = 0; m < 8; m++) sv[tid + m * 512] = cv[tid + m * 512];
    }
    __syncthreads();

    // phase 1: M = w^T w  (M[a][b] = sum_k w[k][a] w[k][b])
    float acc[4][8];
    #pragma unroll
    for (int i = 0; i < 4; i++)
      #pragma unroll
      for (int j = 0; j < 8; j++) acc[i][j] = 0.0f;
    for (int k = 0; k < FF; k++) {
      const float* rp = sM + k * FF;
      float4 a4 = *(const float4*)(rp + a0);
      float4 ba = *(const float4*)(rp + b0);
      float4 bb = *(const float4*)(rp + b0 + 4);
      float av[4] = {a4.x, a4.y, a4.z, a4.w};
      float bv[8] = {ba.x, ba.y, ba.z, ba.w, bb.x, bb.y, bb.z, bb.w};
      #pragma unroll
      for (int i = 0; i < 4; i++)
        #pragma unroll
        for (int j = 0; j < 8; j++) acc[i][j] += av[i] * bv[j];
    }
    __syncthreads();
    #pragma unroll
    for (int i = 0; i < 4; i++) {
      *(float4*)&sM[(a0 + i) * FF + b0]     = make_float4(acc[i][0], acc[i][1], acc[i][2], acc[i][3]);
      *(float4*)&sM[(a0 + i) * FF + b0 + 4] = make_float4(acc[i][4], acc[i][5], acc[i][6], acc[i][7]);
    }
    __syncthreads();

    // phase 2: M2 = M*M via symmetry (M2[a][b] = sum_k M[k][a] M[k][b]); then P over sM
    float acc2[4][8];
    #pragma unroll
    for (int i = 0; i < 4; i++)
      #pragma unroll
      for (int j = 0; j < 8; j++) acc2[i][j] = 0.0f;
    for (int k = 0; k < FF; k++) {
      const float* rp = sM + k * FF;
      float4 a4 = *(const float4*)(rp + a0);
      float4 ba = *(const float4*)(rp + b0);
      float4 bb = *(const float4*)(rp + b0 + 4);
      float av[4] = {a4.x, a4.y, a4.z, a4.w};
      float bv[8] = {ba.x, ba.y, ba.z, ba.w, bb.x, bb.y, bb.z, bb.w};
      #pragma unroll
      for (int i = 0; i < 4; i++)
        #pragma unroll
        for (int j = 0; j < 8; j++) acc2[i][j] += av[i] * bv[j];
    }
    __syncthreads();
    float pv2[4][8];
    #pragma unroll
    for (int i = 0; i < 4; i++)
      #pragma unroll
      for (int j = 0; j < 8; j++) {
        int col = b0 + j;
        float mv = sM[(a0 + i) * FF + col];
        float p = -1.25f * mv + 0.375f * acc2[i][j];
        if (a0 + i == col) p += 1.875f;
        pv2[i][j] = p;
      }
    #pragma unroll
    for (int i = 0; i < 4; i++) {
      *(float4*)&sM[(a0 + i) * FF + b0]     = make_float4(pv2[i][0], pv2[i][1], pv2[i][2], pv2[i][3]);
      *(float4*)&sM[(a0 + i) * FF + b0 + 4] = make_float4(pv2[i][4], pv2[i][5], pv2[i][6], pv2[i][7]);
    }
    __syncthreads();

    // phase 3: nxt = cur * P   (rows a0.., cols b0..)
    float acc3[4][8];
    #pragma unroll
    for (int i = 0; i < 4; i++)
      #pragma unroll
      for (int j = 0; j < 8; j++) acc3[i][j] = 0.0f;
    for (int k0 = 0; k0 < FF; k0 += 4) {
      float wr[4][4];
      #pragma unroll
      for (int r = 0; r < 4; r++) {
        float4 t = *(const float4*)&cur[(a0 + r) * FF + k0];
        wr[r][0] = t.x; wr[r][1] = t.y; wr[r][2] = t.z; wr[r][3] = t.w;
      }
      #pragma unroll
      for (int kk = 0; kk < 4; kk++) {
        const float* pr = &sM[(k0 + kk) * FF + b0];
        float4 pa = *(const float4*)pr;
        float4 pb = *(const float4*)(pr + 4);
        float pv[8] = {pa.x, pa.y, pa.z, pa.w, pb.x, pb.y, pb.z, pb.w};
        #pragma unroll
        for (int r = 0; r < 4; r++)
          #pragma unroll
          for (int c = 0; c < 8; c++) acc3[r][c] += wr[r][kk] * pv[c];
      }
    }
    #pragma unroll
    for (int r = 0; r < 4; r++) {
      *(float4*)&nxt[(a0 + r) * FF + b0]     = make_float4(acc3[r][0], acc3[r][1], acc3[r][2], acc3[r][3]);
      *(float4*)&nxt[(a0 + r) * FF + b0 + 4] = make_float4(acc3[r][4], acc3[r][5], acc3[r][6], acc3[r][7]);
    }
    __syncthreads();
    float* tmp = cur; cur = nxt; nxt = tmp;
  }

  // copy final w (w_final) -> wfin; network uses H = X @ w_final directly
  for (int m = 0; m < 32; m++) {
    int idx = tid + m * 512;
    wfin[idx] = cur[idx];
  }
}

// ---------------- dense GEMM: Out[N][128] = X[N][128] @ Wf[128][128] ----------------
__global__ __launch_bounds__(256) void gemm_xw(const float* __restrict__ X,
    const float* __restrict__ Wf, float* __restrict__ Out) {
  __shared__ float sW[32][FF];
  __shared__ float sX[16][32];
  int tid = threadIdx.x;
  int j = tid & 127;
  int rh = tid >> 7;            // 0/1
  int row0 = blockIdx.x * 16;
  float acc[8] = {0, 0, 0, 0, 0, 0, 0, 0};
  for (int kc = 0; kc < 4; kc++) {
    int k0 = kc * 32;
    #pragma unroll
    for (int m = 0; m < 16; m++) {
      int idx = tid + m * 256;
      int kk = idx >> 7, jj = idx & 127;
      sW[kk][jj] = Wf[(k0 + kk) * FF + jj];
    }
    #pragma unroll
    for (int m = 0; m < 2; m++) {
      int idx = tid + m * 256;
      int rr = idx >> 5, kk = idx & 31;
      sX[rr][kk] = X[(row0 + rr) * FF + k0 + kk];
    }
    __syncthreads();
    for (int k = 0; k < 32; k++) {
      float wv = sW[k][j];
      #pragma unroll
      for (int r = 0; r < 8; r++) acc[r] += sX[rh * 8 + r][k] * wv;
    }
    __syncthreads();
  }
  #pragma unroll
  for (int r = 0; r < 8; r++) Out[(row0 + rh * 8 + r) * FF + j] = acc[r];
}

// ---------------- SpMM + relu: H[c] = relu(d[c] * sum_{e:(r,c)} d[r]*G[r]) ----------------
__global__ __launch_bounds__(128) void spmm_relu(const float* __restrict__ G,
    float* __restrict__ Hout, const float* __restrict__ dinv,
    const int* __restrict__ rowstart, const int* __restrict__ srcl) {
  int row = blockIdx.x;
  int t = threadIdx.x;
  int s = rowstart[row], e = rowstart[row + 1];
  float acc = 0.0f;
  for (int p = s; p < e; p++) {
    int r = srcl[p];
    acc += dinv[r] * G[r * FF + t];
  }
  float v = dinv[row] * acc;
  Hout[row * FF + t] = v > 0.0f ? v : 0.0f;
}

// ---------------- head: logits + log_softmax ----------------
__global__ __launch_bounds__(256) void head_kernel(const float* __restrict__ H,
    const float* __restrict__ lw, const float* __restrict__ lb, float* __restrict__ out) {
  int lane = threadIdx.x & 63;
  int node = blockIdx.x * 4 + (threadIdx.x >> 6);
  float val = 0.0f;
  if (lane < NOUT) {
    val = lb[lane];
    const float* hrow = H + node * FF;
    const float* wrow = lw + lane * FF;
    for (int k = 0; k < FF; k++) val += hrow[k] * wrow[k];
  }
  float m = (lane < NOUT) ? val : -INFINITY;
  for (int off = 32; off; off >>= 1) m = fmaxf(m, __shfl_down(m, off));
  m = __shfl(m, 0);
  float ex = (lane < NOUT) ? expf(val - m) : 0.0f;
  float ssum = ex;
  for (int off = 32; off; off >>= 1) ssum += __shfl_down(ssum, off);
  ssum = __shfl(ssum, 0);
  if (lane < NOUT) out[node * NOUT + lane] = val - m - logf(ssum);
}

extern "C" void kernel_launch(void* const* d_in, const int* in_sizes, int n_in,
                              void* d_out, int out_size, void* d_ws, size_t ws_size,
                              hipStream_t stream) {
  const float* x  = (const float*)d_in[0];
  const float* W1 = (const float*)d_in[1];
  const float* W2 = (const float*)d_in[2];
  const float* lw = (const float*)d_in[3];
  const float* lb = (const float*)d_in[4];
  const int*   ei = (const int*)d_in[5];
  float* out = (float*)d_out;

  float* base = (float*)d_ws;
  float* wb   = base;                 // 2 * 2 * 16384 = 65536 floats (bjorck ping-pong)
  float* wf   = wb + 65536;           // 2 * 16384 final orthonormal weights
  float* degf = wf + 32768;           // NN
  float* dinv = degf + NN;            // NN
  int* cnt      = (int*)(dinv + NN);  // NN
  int* rowstart = cnt + NN;           // NN+1 (padded to 12004)
  int* fill     = rowstart + 12004;   // NN
  int* srcl     = fill + NN;          // EE
  float* bufA = (float*)(srcl + EE);  // NN*FF
  float* bufB = bufA + NN * FF;       // NN*FF

  hipMemsetAsync(degf, 0, NN * sizeof(float), stream);
  hipMemsetAsync(cnt, 0, NN * sizeof(int), stream);
  hipMemsetAsync(fill, 0, NN * sizeof(int), stream);

  build_deg<<<(EE + 255) / 256, 256, 0, stream>>>(ei, degf, cnt);
  scan_kernel<<<1, 1024, 0, stream>>>(cnt, rowstart);
  scatter_edges<<<(EE + 255) / 256, 256, 0, stream>>>(ei, rowstart, fill, srcl);
  dinv_kernel<<<(NN + 255) / 256, 256, 0, stream>>>(degf, dinv);
  bjorck_kernel<<<2, 512, 0, stream>>>(W1, W2, wb, wf);

  gemm_xw<<<NN / 16, 256, 0, stream>>>(x, wf, bufA);
  spmm_relu<<<NN, 128, 0, stream>>>(bufA, bufB, dinv, rowstart, srcl);
  gemm_xw<<<NN / 16, 256, 0, stream>>>(bufB, wf + FF * FF, bufA);
  spmm_relu<<<NN, 128, 0, stream>>>(bufA, bufB, dinv, rowstart, srcl);
  head_kernel<<<NN / 4, 256, 0, stream>>>(bufB, lw, lb, out);
}

// Round 2
// 504.184 us; speedup vs baseline: 2.5599x; 2.5599x over previous
//
#include <hip/hip_runtime.h>
#include <math.h>

#define NN 12000
#define EE 384000
#define FF 128
#define NOUT 40
#define BJ_ITERS 25

typedef __attribute__((ext_vector_type(8))) short bf16x8;
typedef __attribute__((ext_vector_type(4))) short s16x4;
typedef __attribute__((ext_vector_type(4))) float f32x4;
typedef unsigned short ushort_t;

__device__ __forceinline__ ushort_t f2bf(float x) {
  unsigned u = __float_as_uint(x);
  unsigned r = (u + 0x7FFFu + ((u >> 16) & 1u)) >> 16;
  return (ushort_t)r;
}
__device__ __forceinline__ float bf2f(ushort_t h) {
  return __uint_as_float(((unsigned)h) << 16);
}
// swizzled byte offset of element (r, c) in a [128][128] bf16 matrix
__device__ __forceinline__ int swz(int r, int c) {
  return ((r << 8) + (c << 1)) ^ ((r & 7) << 4);
}

// ---------------- degree counting ----------------
__global__ __launch_bounds__(256) void build_deg(const int* __restrict__ ei,
    float* __restrict__ degf, int* __restrict__ cnt) {
  int e = blockIdx.x * 256 + threadIdx.x;
  if (e >= EE) return;
  atomicAdd(&degf[ei[e]], 1.0f);
  atomicAdd(&cnt[ei[EE + e]], 1);
}

// ---------------- exclusive scan ----------------
__global__ __launch_bounds__(1024) void scan_kernel(const int* __restrict__ cnt,
    int* __restrict__ rowstart) {
  __shared__ int sums[1024];
  int tid = threadIdx.x;
  const int CH = 12;
  int base = tid * CH;
  int local[CH];
  int s = 0;
  #pragma unroll
  for (int m = 0; m < CH; m++) {
    int idx = base + m;
    int v = (idx < NN) ? cnt[idx] : 0;
    local[m] = s;
    s += v;
  }
  sums[tid] = s;
  __syncthreads();
  for (int off = 1; off < 1024; off <<= 1) {
    int v = (tid >= off) ? sums[tid - off] : 0;
    __syncthreads();
    sums[tid] += v;
    __syncthreads();
  }
  int excl = (tid > 0) ? sums[tid - 1] : 0;
  #pragma unroll
  for (int m = 0; m < CH; m++) {
    int idx = base + m;
    if (idx < NN) rowstart[idx] = excl + local[m];
  }
  if (tid == 1023) rowstart[NN] = sums[1023];
}

// ---------------- scatter edges into CSR ----------------
__global__ __launch_bounds__(256) void scatter_edges(const int* __restrict__ ei,
    const int* __restrict__ rowstart, int* __restrict__ fill, int* __restrict__ srcl) {
  int e = blockIdx.x * 256 + threadIdx.x;
  if (e >= EE) return;
  int r = ei[e], c = ei[EE + e];
  int pos = rowstart[c] + atomicAdd(&fill[c], 1);
  srcl[pos] = r;
}

__global__ __launch_bounds__(256) void dinv_kernel(const float* __restrict__ degf,
    float* __restrict__ dinv) {
  int i = blockIdx.x * 256 + threadIdx.x;
  if (i >= NN) return;
  float dv = degf[i];
  dinv[i] = (dv > 0.0f) ? (1.0f / sqrtf(dv)) : 0.0f;
}

// ============ MFMA Bjorck ============
// Z = X*Y, X from .R-style buffer (Xh/Xl), Y from .C-style buffer (Yh/Yl).
// A-frag: lane reads X[R0+i*16+(l&15)][k..k+7]; B-frag: lane reads Y.C row (C0+j*16+(l&15)).
__device__ __forceinline__ void mm_product(const char* Xh, const char* Xl,
    const char* Yh, const char* Yl, int R0, int C0, int lane, f32x4 (&acc)[2][4]) {
  int rl = lane & 15;
  int kq = (lane >> 4) * 8;
  #pragma unroll
  for (int k0 = 0; k0 < 128; k0 += 32) {
    bf16x8 ah[2], al[2];
    #pragma unroll
    for (int i = 0; i < 2; i++) {
      ah[i] = *(const bf16x8*)(Xh + swz(R0 + i * 16 + rl, k0 + kq));
      al[i] = *(const bf16x8*)(Xl + swz(R0 + i * 16 + rl, k0 + kq));
    }
    #pragma unroll
    for (int j = 0; j < 4; j++) {
      bf16x8 bh = *(const bf16x8*)(Yh + swz(C0 + j * 16 + rl, k0 + kq));
      bf16x8 bl = *(const bf16x8*)(Yl + swz(C0 + j * 16 + rl, k0 + kq));
      #pragma unroll
      for (int i = 0; i < 2; i++) {
        acc[i][j] = __builtin_amdgcn_mfma_f32_16x16x32_bf16(ah[i], bh, acc[i][j], 0, 0, 0);
        acc[i][j] = __builtin_amdgcn_mfma_f32_16x16x32_bf16(ah[i], bl, acc[i][j], 0, 0, 0);
        acc[i][j] = __builtin_amdgcn_mfma_f32_16x16x32_bf16(al[i], bh, acc[i][j], 0, 0, 0);
      }
    }
  }
}

// natural C-fragment store into a .C-style buffer (stored-row = output col): b64 writes
__device__ __forceinline__ void store_C(char* Ch, char* Cl, int R0, int C0,
    int lane, f32x4 (&acc)[2][4]) {
  int cl = lane & 15, rq = (lane >> 4) * 4;
  #pragma unroll
  for (int i = 0; i < 2; i++)
  #pragma unroll
  for (int j = 0; j < 4; j++) {
    int col = C0 + j * 16 + cl;   // stored row
    int row = R0 + i * 16 + rq;   // stored starting col
    s16x4 hv, lv;
    #pragma unroll
    for (int t = 0; t < 4; t++) {
      float x = acc[i][j][t];
      ushort_t h = f2bf(x);
      ushort_t lo = f2bf(x - bf2f(h));
      hv[t] = (short)h; lv[t] = (short)lo;
    }
    *(s16x4*)(Ch + swz(col, row)) = hv;
    *(s16x4*)(Cl + swz(col, row)) = lv;
  }
}

// scatter store into a .R-style buffer: b16 writes
__device__ __forceinline__ void store_R(char* Rh, char* Rl, int R0, int C0,
    int lane, f32x4 (&acc)[2][4]) {
  int cl = lane & 15, rq = (lane >> 4) * 4;
  #pragma unroll
  for (int i = 0; i < 2; i++)
  #pragma unroll
  for (int j = 0; j < 4; j++) {
    int c = C0 + j * 16 + cl;
    #pragma unroll
    for (int t = 0; t < 4; t++) {
      int r = R0 + i * 16 + rq + t;
      float x = acc[i][j][t];
      ushort_t h = f2bf(x);
      ushort_t lo = f2bf(x - bf2f(h));
      *(ushort_t*)(Rh + swz(r, c)) = h;
      *(ushort_t*)(Rl + swz(r, c)) = lo;
    }
  }
}

// One workgroup (8 waves) per weight. v = w^T state; per iter:
//   M = v v^T ; P = 1.875I - 1.25M + 0.375 M*M ; v' = P v
// LDS: P0 = v.R -> M -> P (overwritten after barriers), P1 = v.C. 128 KiB total.
__global__ __launch_bounds__(512, 2) void bjorck_mfma(const float* __restrict__ W1,
    const float* __restrict__ W2, float* __restrict__ wf) {
  __shared__ char lds[131072];
  char* P0h = lds;
  char* P0l = lds + 32768;
  char* P1h = lds + 65536;
  char* P1l = lds + 98304;
  const int L = blockIdx.x;
  const float* Wsrc = (L == 0) ? W1 : W2;
  float* Wf = wf + L * FF * FF;
  int tid = threadIdx.x;
  int lane = tid & 63;
  int wv = tid >> 6;
  int R0 = (wv >> 1) * 32;       // 2 tile-rows  (rows R0..R0+31)
  int C0 = (wv & 1) * 64;        // 4 tile-cols  (cols C0..C0+63)

  // ---- scaling = 1/sqrt(max_row_abs_sum * max_col_abs_sum) ----
  float* f = (float*)lds;
  if (tid < 256) {
    float s = 0.0f;
    if (tid < 128) {
      for (int j = 0; j < FF; j++) s += fabsf(Wsrc[tid * FF + j]);
    } else {
      int c = tid - 128;
      for (int j = 0; j < FF; j++) s += fabsf(Wsrc[j * FF + c]);
    }
    f[tid] = s;
  }
  __syncthreads();
  if (tid == 0) {
    float rm = 0.0f, cm = 0.0f;
    for (int i = 0; i < 128; i++) { rm = fmaxf(rm, f[i]); cm = fmaxf(cm, f[128 + i]); }
    f[256] = 1.0f / sqrtf(rm * cm);
  }
  __syncthreads();
  float inv_s = f[256];
  __syncthreads();

  // ---- init: v0 = W * inv_s (v = w^T = (W^T/s)^T = W/s). v.R -> P0, v.C -> P1 ----
  {
    int r = tid >> 2, c0 = (tid & 3) * 32;
    #pragma unroll
    for (int mm = 0; mm < 32; mm += 8) {
      bf16x8 hv, lv;
      #pragma unroll
      for (int t = 0; t < 8; t++) {
        float x = Wsrc[r * FF + c0 + mm + t] * inv_s;
        ushort_t h = f2bf(x);
        ushort_t lo = f2bf(x - bf2f(h));
        hv[t] = (short)h; lv[t] = (short)lo;
      }
      *(bf16x8*)(P0h + swz(r, c0 + mm)) = hv;
      *(bf16x8*)(P0l + swz(r, c0 + mm)) = lv;
      #pragma unroll
      for (int t = 0; t < 8; t++) {
        *(ushort_t*)(P1h + swz(c0 + mm + t, r)) = (ushort_t)(unsigned short)hv[t];
        *(ushort_t*)(P1l + swz(c0 + mm + t, r)) = (ushort_t)(unsigned short)lv[t];
      }
    }
  }
  __syncthreads();

  for (int it = 0; it < BJ_ITERS; it++) {
    // phase 1: M = v * v^T   (A: rows of v.R; B: v^T[k][c] = v[c][k] -> rows of v.R)
    f32x4 m_acc[2][4] = {};
    mm_product(P0h, P0l, P0h, P0l, R0, C0, lane, m_acc);
    __syncthreads();
    store_C(P0h, P0l, R0, C0, lane, m_acc);   // M symmetric: .C store == .R
    __syncthreads();

    // phase 2: M2 = M*M (both operands P0; symmetry gives B reads for free)
    f32x4 p_acc[2][4] = {};
    mm_product(P0h, P0l, P0h, P0l, R0, C0, lane, p_acc);
    // P = 1.875 I - 1.25 M + 0.375 M2  (M from registers)
    {
      int cl = lane & 15, rq = (lane >> 4) * 4;
      #pragma unroll
      for (int i = 0; i < 2; i++)
      #pragma unroll
      for (int j = 0; j < 4; j++)
      #pragma unroll
      for (int t = 0; t < 4; t++) {
        int row = R0 + i * 16 + rq + t;
        int col = C0 + j * 16 + cl;
        float pv = -1.25f * m_acc[i][j][t] + 0.375f * p_acc[i][j][t];
        if (row == col) pv += 1.875f;
        p_acc[i][j][t] = pv;
      }
    }
    __syncthreads();
    store_C(P0h, P0l, R0, C0, lane, p_acc);   // P symmetric
    __syncthreads();

    // phase 3: v' = P * v   (A: rows of P from P0; B: v[k][c] from v.C = P1)
    f32x4 v_acc[2][4] = {};
    mm_product(P0h, P0l, P1h, P1l, R0, C0, lane, v_acc);
    __syncthreads();
    if (it == BJ_ITERS - 1) {
      // Wf[k][j] = w_bj[k][j] = v[j][k]: lane writes Wf[col][row..row+3]
      int cl = lane & 15, rq = (lane >> 4) * 4;
      #pragma unroll
      for (int i = 0; i < 2; i++)
      #pragma unroll
      for (int j = 0; j < 4; j++) {
        int col = C0 + j * 16 + cl;
        int row = R0 + i * 16 + rq;
        *(f32x4*)(Wf + col * FF + row) = v_acc[i][j];
      }
    } else {
      store_C(P1h, P1l, R0, C0, lane, v_acc);  // v'.C
      store_R(P0h, P0l, R0, C0, lane, v_acc);  // v'.R
    }
    __syncthreads();
  }
}

// ---------------- dense GEMM: Out[N][128] = X[N][128] @ Wf[128][128] ----------------
__global__ __launch_bounds__(256) void gemm_xw(const float* __restrict__ X,
    const float* __restrict__ Wf, float* __restrict__ Out) {
  __shared__ float sW[32][FF];
  __shared__ float sX[16][32];
  int tid = threadIdx.x;
  int j = tid & 127;
  int rh = tid >> 7;
  int row0 = blockIdx.x * 16;
  float acc[8] = {0, 0, 0, 0, 0, 0, 0, 0};
  for (int kc = 0; kc < 4; kc++) {
    int k0 = kc * 32;
    #pragma unroll
    for (int m = 0; m < 16; m++) {
      int idx = tid + m * 256;
      int kk = idx >> 7, jj = idx & 127;
      sW[kk][jj] = Wf[(k0 + kk) * FF + jj];
    }
    #pragma unroll
    for (int m = 0; m < 2; m++) {
      int idx = tid + m * 256;
      int rr = idx >> 5, kk = idx & 31;
      sX[rr][kk] = X[(row0 + rr) * FF + k0 + kk];
    }
    __syncthreads();
    for (int k = 0; k < 32; k++) {
      float wv = sW[k][j];
      #pragma unroll
      for (int r = 0; r < 8; r++) acc[r] += sX[rh * 8 + r][k] * wv;
    }
    __syncthreads();
  }
  #pragma unroll
  for (int r = 0; r < 8; r++) Out[(row0 + rh * 8 + r) * FF + j] = acc[r];
}

// ---------------- SpMM + relu ----------------
__global__ __launch_bounds__(128) void spmm_relu(const float* __restrict__ G,
    float* __restrict__ Hout, const float* __restrict__ dinv,
    const int* __restrict__ rowstart, const int* __restrict__ srcl) {
  int row = blockIdx.x;
  int t = threadIdx.x;
  int s = rowstart[row], e = rowstart[row + 1];
  float acc = 0.0f;
  for (int p = s; p < e; p++) {
    int r = srcl[p];
    acc += dinv[r] * G[r * FF + t];
  }
  float v = dinv[row] * acc;
  Hout[row * FF + t] = v > 0.0f ? v : 0.0f;
}

// ---------------- head: logits + log_softmax ----------------
__global__ __launch_bounds__(256) void head_kernel(const float* __restrict__ H,
    const float* __restrict__ lw, const float* __restrict__ lb, float* __restrict__ out) {
  int lane = threadIdx.x & 63;
  int node = blockIdx.x * 4 + (threadIdx.x >> 6);
  float val = 0.0f;
  if (lane < NOUT) {
    val = lb[lane];
    const float* hrow = H + node * FF;
    const float* wrow = lw + lane * FF;
    for (int k = 0; k < FF; k++) val += hrow[k] * wrow[k];
  }
  float m = (lane < NOUT) ? val : -INFINITY;
  for (int off = 32; off; off >>= 1) m = fmaxf(m, __shfl_down(m, off));
  m = __shfl(m, 0);
  float ex = (lane < NOUT) ? expf(val - m) : 0.0f;
  float ssum = ex;
  for (int off = 32; off; off >>= 1) ssum += __shfl_down(ssum, off);
  ssum = __shfl(ssum, 0);
  if (lane < NOUT) out[node * NOUT + lane] = val - m - logf(ssum);
}

extern "C" void kernel_launch(void* const* d_in, const int* in_sizes, int n_in,
                              void* d_out, int out_size, void* d_ws, size_t ws_size,
                              hipStream_t stream) {
  const float* x  = (const float*)d_in[0];
  const float* W1 = (const float*)d_in[1];
  const float* W2 = (const float*)d_in[2];
  const float* lw = (const float*)d_in[3];
  const float* lb = (const float*)d_in[4];
  const int*   ei = (const int*)d_in[5];
  float* out = (float*)d_out;

  float* base = (float*)d_ws;
  float* wb   = base;                 // (unused now; kept for layout stability)
  float* wf   = wb + 65536;           // 2 * 16384 final orthonormal weights
  float* degf = wf + 32768;           // NN
  float* dinv = degf + NN;            // NN
  int* cnt      = (int*)(dinv + NN);  // NN
  int* rowstart = cnt + NN;           // NN+1 (padded to 12004)
  int* fill     = rowstart + 12004;   // NN
  int* srcl     = fill + NN;          // EE
  float* bufA = (float*)(srcl + EE);  // NN*FF
  float* bufB = bufA + NN * FF;       // NN*FF

  hipMemsetAsync(degf, 0, NN * sizeof(float), stream);
  hipMemsetAsync(cnt, 0, NN * sizeof(int), stream);
  hipMemsetAsync(fill, 0, NN * sizeof(int), stream);

  build_deg<<<(EE + 255) / 256, 256, 0, stream>>>(ei, degf, cnt);
  scan_kernel<<<1, 1024, 0, stream>>>(cnt, rowstart);
  scatter_edges<<<(EE + 255) / 256, 256, 0, stream>>>(ei, rowstart, fill, srcl);
  dinv_kernel<<<(NN + 255) / 256, 256, 0, stream>>>(degf, dinv);
  bjorck_mfma<<<2, 512, 0, stream>>>(W1, W2, wf);

  gemm_xw<<<NN / 16, 256, 0, stream>>>(x, wf, bufA);
  spmm_relu<<<NN, 128, 0, stream>>>(bufA, bufB, dinv, rowstart, srcl);
  gemm_xw<<<NN / 16, 256, 0, stream>>>(bufB, wf + FF * FF, bufA);
  spmm_relu<<<NN, 128, 0, stream>>>(bufA, bufB, dinv, rowstart, srcl);
  head_kernel<<<NN / 4, 256, 0, stream>>>(bufB, lw, lb, out);
}

// Round 3
// 398.862 us; speedup vs baseline: 3.2359x; 1.2641x over previous
//
#include <hip/hip_runtime.h>
#include <math.h>

#define NN 12000
#define EE 384000
#define FF 128
#define NOUT 40
#define BJ_ITERS 25

typedef __attribute__((ext_vector_type(8))) short bf16x8;
typedef __attribute__((ext_vector_type(4))) short s16x4;
typedef __attribute__((ext_vector_type(4))) float f32x4;
typedef unsigned short ushort_t;

__device__ __forceinline__ ushort_t f2bf(float x) {
  unsigned u = __float_as_uint(x);
  unsigned r = (u + 0x7FFFu + ((u >> 16) & 1u)) >> 16;
  return (ushort_t)r;
}
__device__ __forceinline__ float bf2f(ushort_t h) {
  return __uint_as_float(((unsigned)h) << 16);
}
// swizzled byte offset of element (r, c) in a row-major [*][128] bf16 plane
__device__ __forceinline__ int swz(int r, int c) {
  return ((r << 8) + (c << 1)) ^ ((r & 7) << 4);
}

// ---------------- degree counting ----------------
__global__ __launch_bounds__(256) void build_deg(const int* __restrict__ ei,
    float* __restrict__ degf, int* __restrict__ cnt) {
  int e = blockIdx.x * 256 + threadIdx.x;
  if (e >= EE) return;
  atomicAdd(&degf[ei[e]], 1.0f);
  atomicAdd(&cnt[ei[EE + e]], 1);
}

// ---------------- exclusive scan ----------------
__global__ __launch_bounds__(1024) void scan_kernel(const int* __restrict__ cnt,
    int* __restrict__ rowstart) {
  __shared__ int sums[1024];
  int tid = threadIdx.x;
  const int CH = 12;
  int base = tid * CH;
  int local[CH];
  int s = 0;
  #pragma unroll
  for (int m = 0; m < CH; m++) {
    int idx = base + m;
    int v = (idx < NN) ? cnt[idx] : 0;
    local[m] = s;
    s += v;
  }
  sums[tid] = s;
  __syncthreads();
  for (int off = 1; off < 1024; off <<= 1) {
    int v = (tid >= off) ? sums[tid - off] : 0;
    __syncthreads();
    sums[tid] += v;
    __syncthreads();
  }
  int excl = (tid > 0) ? sums[tid - 1] : 0;
  #pragma unroll
  for (int m = 0; m < CH; m++) {
    int idx = base + m;
    if (idx < NN) rowstart[idx] = excl + local[m];
  }
  if (tid == 1023) rowstart[NN] = sums[1023];
}

// ---------------- scatter edges into CSR ----------------
__global__ __launch_bounds__(256) void scatter_edges(const int* __restrict__ ei,
    const int* __restrict__ rowstart, int* __restrict__ fill, int* __restrict__ srcl) {
  int e = blockIdx.x * 256 + threadIdx.x;
  if (e >= EE) return;
  int r = ei[e], c = ei[EE + e];
  int pos = rowstart[c] + atomicAdd(&fill[c], 1);
  srcl[pos] = r;
}

__global__ __launch_bounds__(256) void dinv_kernel(const float* __restrict__ degf,
    float* __restrict__ dinv) {
  int i = blockIdx.x * 256 + threadIdx.x;
  if (i >= NN) return;
  float dv = degf[i];
  dinv[i] = (dv > 0.0f) ? (1.0f / sqrtf(dv)) : 0.0f;
}

// ============ MFMA Bjorck ============
__device__ __forceinline__ void mm_product(const char* Xh, const char* Xl,
    const char* Yh, const char* Yl, int R0, int C0, int lane, f32x4 (&acc)[2][4]) {
  int rl = lane & 15;
  int kq = (lane >> 4) * 8;
  #pragma unroll
  for (int k0 = 0; k0 < 128; k0 += 32) {
    bf16x8 ah[2], al[2];
    #pragma unroll
    for (int i = 0; i < 2; i++) {
      ah[i] = *(const bf16x8*)(Xh + swz(R0 + i * 16 + rl, k0 + kq));
      al[i] = *(const bf16x8*)(Xl + swz(R0 + i * 16 + rl, k0 + kq));
    }
    #pragma unroll
    for (int j = 0; j < 4; j++) {
      bf16x8 bh = *(const bf16x8*)(Yh + swz(C0 + j * 16 + rl, k0 + kq));
      bf16x8 bl = *(const bf16x8*)(Yl + swz(C0 + j * 16 + rl, k0 + kq));
      #pragma unroll
      for (int i = 0; i < 2; i++) {
        acc[i][j] = __builtin_amdgcn_mfma_f32_16x16x32_bf16(ah[i], bh, acc[i][j], 0, 0, 0);
        acc[i][j] = __builtin_amdgcn_mfma_f32_16x16x32_bf16(ah[i], bl, acc[i][j], 0, 0, 0);
        acc[i][j] = __builtin_amdgcn_mfma_f32_16x16x32_bf16(al[i], bh, acc[i][j], 0, 0, 0);
      }
    }
  }
}

__device__ __forceinline__ void store_C(char* Ch, char* Cl, int R0, int C0,
    int lane, f32x4 (&acc)[2][4]) {
  int cl = lane & 15, rq = (lane >> 4) * 4;
  #pragma unroll
  for (int i = 0; i < 2; i++)
  #pragma unroll
  for (int j = 0; j < 4; j++) {
    int col = C0 + j * 16 + cl;
    int row = R0 + i * 16 + rq;
    s16x4 hv, lv;
    #pragma unroll
    for (int t = 0; t < 4; t++) {
      float x = acc[i][j][t];
      ushort_t h = f2bf(x);
      ushort_t lo = f2bf(x - bf2f(h));
      hv[t] = (short)h; lv[t] = (short)lo;
    }
    *(s16x4*)(Ch + swz(col, row)) = hv;
    *(s16x4*)(Cl + swz(col, row)) = lv;
  }
}

__device__ __forceinline__ void store_R(char* Rh, char* Rl, int R0, int C0,
    int lane, f32x4 (&acc)[2][4]) {
  int cl = lane & 15, rq = (lane >> 4) * 4;
  #pragma unroll
  for (int i = 0; i < 2; i++)
  #pragma unroll
  for (int j = 0; j < 4; j++) {
    int c = C0 + j * 16 + cl;
    #pragma unroll
    for (int t = 0; t < 4; t++) {
      int r = R0 + i * 16 + rq + t;
      float x = acc[i][j][t];
      ushort_t h = f2bf(x);
      ushort_t lo = f2bf(x - bf2f(h));
      *(ushort_t*)(Rh + swz(r, c)) = h;
      *(ushort_t*)(Rl + swz(r, c)) = lo;
    }
  }
}

// One workgroup (8 waves) per weight; outputs row-major v as bf16 h/l planes
// (= the .C operand layout of orth(W)^T for the downstream GEMM).
// Early-exit: once max|v v^T - I| < 1e-4, remaining reference iterations are
// identity maps to well below output tolerance (cubic convergence).
__global__ __launch_bounds__(512) void bjorck_mfma(const float* __restrict__ W1,
    const float* __restrict__ W2, ushort_t* __restrict__ wfc) {
  __shared__ char lds[131072];
  __shared__ float wmax[8];
  char* P0h = lds;
  char* P0l = lds + 32768;
  char* P1h = lds + 65536;
  char* P1l = lds + 98304;
  const int L = blockIdx.x;
  const float* Wsrc = (L == 0) ? W1 : W2;
  int tid = threadIdx.x;
  int lane = tid & 63;
  int wv = tid >> 6;
  int R0 = (wv >> 1) * 32;
  int C0 = (wv & 1) * 64;

  // ---- scaling ----
  float* f = (float*)lds;
  if (tid < 256) {
    float s = 0.0f;
    if (tid < 128) {
      for (int j = 0; j < FF; j++) s += fabsf(Wsrc[tid * FF + j]);
    } else {
      int c = tid - 128;
      for (int j = 0; j < FF; j++) s += fabsf(Wsrc[j * FF + c]);
    }
    f[tid] = s;
  }
  __syncthreads();
  if (tid == 0) {
    float rm = 0.0f, cm = 0.0f;
    for (int i = 0; i < 128; i++) { rm = fmaxf(rm, f[i]); cm = fmaxf(cm, f[128 + i]); }
    f[256] = 1.0f / sqrtf(rm * cm);
  }
  __syncthreads();
  float inv_s = f[256];
  __syncthreads();

  // ---- init: v0 = W * inv_s. v.R -> P0, v.C -> P1 ----
  {
    int r = tid >> 2, c0 = (tid & 3) * 32;
    #pragma unroll
    for (int mm = 0; mm < 32; mm += 8) {
      bf16x8 hv, lv;
      #pragma unroll
      for (int t = 0; t < 8; t++) {
        float x = Wsrc[r * FF + c0 + mm + t] * inv_s;
        ushort_t h = f2bf(x);
        ushort_t lo = f2bf(x - bf2f(h));
        hv[t] = (short)h; lv[t] = (short)lo;
      }
      *(bf16x8*)(P0h + swz(r, c0 + mm)) = hv;
      *(bf16x8*)(P0l + swz(r, c0 + mm)) = lv;
      #pragma unroll
      for (int t = 0; t < 8; t++) {
        *(ushort_t*)(P1h + swz(c0 + mm + t, r)) = (ushort_t)(unsigned short)hv[t];
        *(ushort_t*)(P1l + swz(c0 + mm + t, r)) = (ushort_t)(unsigned short)lv[t];
      }
    }
  }
  __syncthreads();

  for (int it = 0; it < BJ_ITERS; it++) {
    // phase 1: M = v * v^T
    f32x4 m_acc[2][4] = {};
    mm_product(P0h, P0l, P0h, P0l, R0, C0, lane, m_acc);

    // convergence check: max |M - I|
    {
      int cl = lane & 15, rq = (lane >> 4) * 4;
      float lmax = 0.0f;
      #pragma unroll
      for (int i = 0; i < 2; i++)
      #pragma unroll
      for (int j = 0; j < 4; j++)
      #pragma unroll
      for (int t = 0; t < 4; t++) {
        int row = R0 + i * 16 + rq + t;
        int col = C0 + j * 16 + cl;
        float d = m_acc[i][j][t] - ((row == col) ? 1.0f : 0.0f);
        lmax = fmaxf(lmax, fabsf(d));
      }
      #pragma unroll
      for (int off = 32; off; off >>= 1) lmax = fmaxf(lmax, __shfl_xor(lmax, off));
      if (lane == 0) wmax[wv] = lmax;
    }
    __syncthreads();
    {
      float gmax = 0.0f;
      #pragma unroll
      for (int w = 0; w < 8; w++) gmax = fmaxf(gmax, wmax[w]);
      if (gmax < 1e-4f) break;   // v already orthonormal to tolerance
    }
    store_C(P0h, P0l, R0, C0, lane, m_acc);   // M symmetric
    __syncthreads();

    // phase 2: M2 = M*M; P = 1.875I - 1.25M + 0.375M2
    f32x4 p_acc[2][4] = {};
    mm_product(P0h, P0l, P0h, P0l, R0, C0, lane, p_acc);
    {
      int cl = lane & 15, rq = (lane >> 4) * 4;
      #pragma unroll
      for (int i = 0; i < 2; i++)
      #pragma unroll
      for (int j = 0; j < 4; j++)
      #pragma unroll
      for (int t = 0; t < 4; t++) {
        int row = R0 + i * 16 + rq + t;
        int col = C0 + j * 16 + cl;
        float pv = -1.25f * m_acc[i][j][t] + 0.375f * p_acc[i][j][t];
        if (row == col) pv += 1.875f;
        p_acc[i][j][t] = pv;
      }
    }
    __syncthreads();
    store_C(P0h, P0l, R0, C0, lane, p_acc);   // P symmetric
    __syncthreads();

    // phase 3: v' = P * v
    f32x4 v_acc[2][4] = {};
    mm_product(P0h, P0l, P1h, P1l, R0, C0, lane, v_acc);
    __syncthreads();
    store_C(P1h, P1l, R0, C0, lane, v_acc);
    store_R(P0h, P0l, R0, C0, lane, v_acc);
    __syncthreads();
  }

  // writeout: row-major v bf16 planes from P0 (unswizzle)
  {
    ushort_t* oh = wfc + L * 32768;
    ushort_t* ol = oh + 16384;
    int r = tid >> 2;
    int q = tid & 3;
    #pragma unroll
    for (int b = 0; b < 4; b++) {
      int c0 = q * 32 + b * 8;
      bf16x8 hv = *(const bf16x8*)(P0h + swz(r, c0));
      bf16x8 lv = *(const bf16x8*)(P0l + swz(r, c0));
      *(bf16x8*)(oh + r * FF + c0) = hv;
      *(bf16x8*)(ol + r * FF + c0) = lv;
    }
  }
}

// ---------------- MFMA GEMM: Out[N][128] = X @ v^T, B-planes from global ----------------
__global__ __launch_bounds__(256) void gemm_mfma(const float* __restrict__ X,
    const ushort_t* __restrict__ wc, float* __restrict__ Out) {
  __shared__ char xlds[32768];
  char* Xh = xlds;
  char* Xl = xlds + 16384;
  int tid = threadIdx.x;
  int row0 = blockIdx.x * 64;

  // stage + split X rows row0..row0+63
  {
    int r = tid >> 2;
    int q = (tid & 3) * 32;
    int gr = row0 + r;
    #pragma unroll
    for (int b = 0; b < 32; b += 8) {
      bf16x8 hv, lv;
      if (gr < NN) {
        const float* xp = X + gr * FF + q + b;
        #pragma unroll
        for (int t = 0; t < 8; t++) {
          float xv = xp[t];
          ushort_t h = f2bf(xv);
          hv[t] = (short)h;
          lv[t] = (short)f2bf(xv - bf2f(h));
        }
      } else {
        #pragma unroll
        for (int t = 0; t < 8; t++) { hv[t] = 0; lv[t] = 0; }
      }
      *(bf16x8*)(Xh + swz(r, q + b)) = hv;
      *(bf16x8*)(Xl + swz(r, q + b)) = lv;
    }
  }
  __syncthreads();

  int lane = tid & 63, wv = tid >> 6;
  int R0 = (wv & 1) * 32;
  int C0 = (wv >> 1) * 64;
  int rl = lane & 15, kq = (lane >> 4) * 8;
  f32x4 acc[2][4] = {};
  #pragma unroll
  for (int k0 = 0; k0 < 128; k0 += 32) {
    bf16x8 ah[2], al[2];
    #pragma unroll
    for (int i = 0; i < 2; i++) {
      ah[i] = *(const bf16x8*)(Xh + swz(R0 + i * 16 + rl, k0 + kq));
      al[i] = *(const bf16x8*)(Xl + swz(R0 + i * 16 + rl, k0 + kq));
    }
    #pragma unroll
    for (int j = 0; j < 4; j++) {
      const ushort_t* bp = wc + (C0 + j * 16 + rl) * FF + k0 + kq;
      bf16x8 bh = *(const bf16x8*)bp;
      bf16x8 bl = *(const bf16x8*)(bp + 16384);
      #pragma unroll
      for (int i = 0; i < 2; i++) {
        acc[i][j] = __builtin_amdgcn_mfma_f32_16x16x32_bf16(ah[i], bh, acc[i][j], 0, 0, 0);
        acc[i][j] = __builtin_amdgcn_mfma_f32_16x16x32_bf16(ah[i], bl, acc[i][j], 0, 0, 0);
        acc[i][j] = __builtin_amdgcn_mfma_f32_16x16x32_bf16(al[i], bh, acc[i][j], 0, 0, 0);
      }
    }
  }
  int rq = (lane >> 4) * 4;
  #pragma unroll
  for (int i = 0; i < 2; i++)
  #pragma unroll
  for (int j = 0; j < 4; j++) {
    int col = C0 + j * 16 + rl;
    #pragma unroll
    for (int t = 0; t < 4; t++) {
      int node = row0 + R0 + i * 16 + rq + t;
      if (node < NN) Out[node * FF + col] = acc[i][j][t];
    }
  }
}

// ---------------- SpMM + relu: 8 rows/block, float4 per 32-lane group ----------------
__global__ __launch_bounds__(256) void spmm_relu(const float* __restrict__ G,
    float* __restrict__ Hout, const float* __restrict__ dinv,
    const int* __restrict__ rowstart, const int* __restrict__ srcl) {
  int g = threadIdx.x >> 5;
  int lane = threadIdx.x & 31;
  int row = blockIdx.x * 8 + g;
  int s = rowstart[row], e = rowstart[row + 1];
  const float4* G4 = (const float4*)G;
  float4 acc = make_float4(0.f, 0.f, 0.f, 0.f);
  for (int p = s; p < e; p++) {
    int r = srcl[p];
    float dr = dinv[r];
    float4 gv = G4[r * 32 + lane];
    acc.x += dr * gv.x; acc.y += dr * gv.y; acc.z += dr * gv.z; acc.w += dr * gv.w;
  }
  float dc = dinv[row];
  float4 o;
  o.x = fmaxf(dc * acc.x, 0.f); o.y = fmaxf(dc * acc.y, 0.f);
  o.z = fmaxf(dc * acc.z, 0.f); o.w = fmaxf(dc * acc.w, 0.f);
  ((float4*)Hout)[row * 32 + lane] = o;
}

// ---------------- head: LDS-staged lw (stride 130, b64 reads) + log_softmax ----------------
__global__ __launch_bounds__(256) void head_kernel(const float* __restrict__ H,
    const float* __restrict__ lw, const float* __restrict__ lb, float* __restrict__ out) {
  __shared__ float slw[64 * 130];
  __shared__ float slb[64];
  int tid = threadIdx.x;
  for (int i = tid; i < 64 * 128; i += 256) {
    int r = i >> 7, c = i & 127;
    slw[r * 130 + c] = (r < NOUT) ? lw[r * FF + c] : 0.0f;
  }
  if (tid < 64) slb[tid] = (tid < NOUT) ? lb[tid] : 0.0f;
  __syncthreads();

  int lane = tid & 63;
  int node = blockIdx.x * 4 + (tid >> 6);
  const float2* hrow = (const float2*)(H + node * FF);
  const float2* wrow = (const float2*)(slw + lane * 130);
  float val = slb[lane];
  #pragma unroll 4
  for (int k = 0; k < 64; k++) {
    float2 w2 = wrow[k];
    float2 h2 = hrow[k];
    val += w2.x * h2.x + w2.y * h2.y;
  }
  float m = (lane < NOUT) ? val : -INFINITY;
  for (int off = 32; off; off >>= 1) m = fmaxf(m, __shfl_down(m, off));
  m = __shfl(m, 0);
  float ex = (lane < NOUT) ? expf(val - m) : 0.0f;
  float ssum = ex;
  for (int off = 32; off; off >>= 1) ssum += __shfl_down(ssum, off);
  ssum = __shfl(ssum, 0);
  if (lane < NOUT) out[node * NOUT + lane] = val - m - logf(ssum);
}

extern "C" void kernel_launch(void* const* d_in, const int* in_sizes, int n_in,
                              void* d_out, int out_size, void* d_ws, size_t ws_size,
                              hipStream_t stream) {
  const float* x  = (const float*)d_in[0];
  const float* W1 = (const float*)d_in[1];
  const float* W2 = (const float*)d_in[2];
  const float* lw = (const float*)d_in[3];
  const float* lb = (const float*)d_in[4];
  const int*   ei = (const int*)d_in[5];
  float* out = (float*)d_out;

  float* base = (float*)d_ws;
  float* wb   = base;                 // 65536 floats (spare)
  float* wf   = wb + 65536;           // 32768 floats -> holds bf16 planes (2 weights)
  float* degf = wf + 32768;           // NN
  float* dinv = degf + NN;            // NN
  int* cnt      = (int*)(dinv + NN);
  int* rowstart = cnt + NN;           // NN+1 (padded to 12004)
  int* fill     = rowstart + 12004;
  int* srcl     = fill + NN;          // EE
  float* bufA = (float*)(srcl + EE);  // NN*FF
  float* bufB = bufA + NN * FF;       // NN*FF
  ushort_t* wfc = (ushort_t*)wf;      // per weight: 32768 shorts (h 16384, l 16384)

  hipMemsetAsync(degf, 0, NN * sizeof(float), stream);
  hipMemsetAsync(cnt, 0, NN * sizeof(int), stream);
  hipMemsetAsync(fill, 0, NN * sizeof(int), stream);

  build_deg<<<(EE + 255) / 256, 256, 0, stream>>>(ei, degf, cnt);
  scan_kernel<<<1, 1024, 0, stream>>>(cnt, rowstart);
  scatter_edges<<<(EE + 255) / 256, 256, 0, stream>>>(ei, rowstart, fill, srcl);
  dinv_kernel<<<(NN + 255) / 256, 256, 0, stream>>>(degf, dinv);
  bjorck_mfma<<<2, 512, 0, stream>>>(W1, W2, wfc);

  gemm_mfma<<<(NN + 63) / 64, 256, 0, stream>>>(x, wfc, bufA);
  spmm_relu<<<NN / 8, 256, 0, stream>>>(bufA, bufB, dinv, rowstart, srcl);
  gemm_mfma<<<(NN + 63) / 64, 256, 0, stream>>>(bufB, wfc + 32768, bufA);
  spmm_relu<<<NN / 8, 256, 0, stream>>>(bufA, bufB, dinv, rowstart, srcl);
  head_kernel<<<NN / 4, 256, 0, stream>>>(bufB, lw, lb, out);
}

// Round 4
// 313.459 us; speedup vs baseline: 4.1175x; 1.2725x over previous
//
#include <hip/hip_runtime.h>
#include <math.h>

#define NN 12000
#define EE 384000
#define FF 128
#define NOUT 40
#define BJ_MAX 25
#define NWARM 8

typedef __attribute__((ext_vector_type(8))) short bf16x8;
typedef __attribute__((ext_vector_type(4))) short s16x4;
typedef __attribute__((ext_vector_type(4))) float f32x4;
typedef unsigned short ushort_t;

__device__ __forceinline__ ushort_t f2bf(float x) {
  unsigned u = __float_as_uint(x);
  unsigned r = (u + 0x7FFFu + ((u >> 16) & 1u)) >> 16;
  return (ushort_t)r;
}
__device__ __forceinline__ float bf2f(ushort_t h) {
  return __uint_as_float(((unsigned)h) << 16);
}
// swizzled byte offset of element (r, c) in a row-major [*][128] bf16 plane
__device__ __forceinline__ int swz(int r, int c) {
  return ((r << 8) + (c << 1)) ^ ((r & 7) << 4);
}

// ---------------- degree counting ----------------
__global__ __launch_bounds__(256) void build_deg(const int* __restrict__ ei,
    float* __restrict__ degf, int* __restrict__ cnt) {
  int e = blockIdx.x * 256 + threadIdx.x;
  if (e >= EE) return;
  atomicAdd(&degf[ei[e]], 1.0f);
  atomicAdd(&cnt[ei[EE + e]], 1);
}

// ---------------- exclusive scan + fused dinv ----------------
__global__ __launch_bounds__(1024) void scan_dinv_kernel(const int* __restrict__ cnt,
    int* __restrict__ rowstart, const float* __restrict__ degf, float* __restrict__ dinv) {
  __shared__ int sums[1024];
  int tid = threadIdx.x;
  const int CH = 12;
  int base = tid * CH;
  int local[CH];
  int s = 0;
  #pragma unroll
  for (int m = 0; m < CH; m++) {
    int idx = base + m;
    int v = (idx < NN) ? cnt[idx] : 0;
    local[m] = s;
    s += v;
  }
  sums[tid] = s;
  __syncthreads();
  for (int off = 1; off < 1024; off <<= 1) {
    int v = (tid >= off) ? sums[tid - off] : 0;
    __syncthreads();
    sums[tid] += v;
    __syncthreads();
  }
  int excl = (tid > 0) ? sums[tid - 1] : 0;
  #pragma unroll
  for (int m = 0; m < CH; m++) {
    int idx = base + m;
    if (idx < NN) rowstart[idx] = excl + local[m];
  }
  if (tid == 1023) rowstart[NN] = sums[1023];
  // fused dinv (independent of the scan; degf final after build_deg)
  for (int i = tid; i < NN; i += 1024) {
    float dv = degf[i];
    dinv[i] = (dv > 0.0f) ? (1.0f / sqrtf(dv)) : 0.0f;
  }
}

// ---------------- scatter edges into CSR ----------------
__global__ __launch_bounds__(256) void scatter_edges(const int* __restrict__ ei,
    const int* __restrict__ rowstart, int* __restrict__ fill, int* __restrict__ srcl) {
  int e = blockIdx.x * 256 + threadIdx.x;
  if (e >= EE) return;
  int r = ei[e], c = ei[EE + e];
  int pos = rowstart[c] + atomicAdd(&fill[c], 1);
  srcl[pos] = r;
}

// ============ MFMA Bjorck ============
__device__ __forceinline__ void mm_product(const char* Xh, const char* Xl,
    const char* Yh, const char* Yl, int R0, int C0, int lane, f32x4 (&acc)[2][4]) {
  int rl = lane & 15;
  int kq = (lane >> 4) * 8;
  #pragma unroll
  for (int k0 = 0; k0 < 128; k0 += 32) {
    bf16x8 ah[2], al[2];
    #pragma unroll
    for (int i = 0; i < 2; i++) {
      ah[i] = *(const bf16x8*)(Xh + swz(R0 + i * 16 + rl, k0 + kq));
      al[i] = *(const bf16x8*)(Xl + swz(R0 + i * 16 + rl, k0 + kq));
    }
    #pragma unroll
    for (int j = 0; j < 4; j++) {
      bf16x8 bh = *(const bf16x8*)(Yh + swz(C0 + j * 16 + rl, k0 + kq));
      bf16x8 bl = *(const bf16x8*)(Yl + swz(C0 + j * 16 + rl, k0 + kq));
      #pragma unroll
      for (int i = 0; i < 2; i++) {
        acc[i][j] = __builtin_amdgcn_mfma_f32_16x16x32_bf16(ah[i], bh, acc[i][j], 0, 0, 0);
        acc[i][j] = __builtin_amdgcn_mfma_f32_16x16x32_bf16(ah[i], bl, acc[i][j], 0, 0, 0);
        acc[i][j] = __builtin_amdgcn_mfma_f32_16x16x32_bf16(al[i], bh, acc[i][j], 0, 0, 0);
      }
    }
  }
}

__device__ __forceinline__ void store_C(char* Ch, char* Cl, int R0, int C0,
    int lane, f32x4 (&acc)[2][4]) {
  int cl = lane & 15, rq = (lane >> 4) * 4;
  #pragma unroll
  for (int i = 0; i < 2; i++)
  #pragma unroll
  for (int j = 0; j < 4; j++) {
    int col = C0 + j * 16 + cl;
    int row = R0 + i * 16 + rq;
    s16x4 hv, lv;
    #pragma unroll
    for (int t = 0; t < 4; t++) {
      float x = acc[i][j][t];
      ushort_t h = f2bf(x);
      ushort_t lo = f2bf(x - bf2f(h));
      hv[t] = (short)h; lv[t] = (short)lo;
    }
    *(s16x4*)(Ch + swz(col, row)) = hv;
    *(s16x4*)(Cl + swz(col, row)) = lv;
  }
}

__device__ __forceinline__ void store_R(char* Rh, char* Rl, int R0, int C0,
    int lane, f32x4 (&acc)[2][4]) {
  int cl = lane & 15, rq = (lane >> 4) * 4;
  #pragma unroll
  for (int i = 0; i < 2; i++)
  #pragma unroll
  for (int j = 0; j < 4; j++) {
    int c = C0 + j * 16 + cl;
    #pragma unroll
    for (int t = 0; t < 4; t++) {
      int r = R0 + i * 16 + rq + t;
      float x = acc[i][j][t];
      ushort_t h = f2bf(x);
      ushort_t lo = f2bf(x - bf2f(h));
      *(ushort_t*)(Rh + swz(r, c)) = h;
      *(ushort_t*)(Rl + swz(r, c)) = lo;
    }
  }
}

// One workgroup (8 waves) per weight. Iteration: v' = (ca*I + cb*M + cc*M^2) v,
// M = v v^T. First NWARM iterations use aggressive Newton-Schulz coefficients
// (Muon: 3.4445, -4.775, 2.0315 — stable on [0,1.21] under composition, gain
// 3.44x/iter on small sigma); then standard Bjorck order-2 (1.875,-1.25,0.375)
// until max|M - I| < 1e-4. All iterates are odd polynomials of the same W ->
// identical singular vectors; the exit check certifies sigma ~ 1, so the
// result matches the reference's converged polar factor within tolerance.
__global__ __launch_bounds__(512) void bjorck_mfma(const float* __restrict__ W1,
    const float* __restrict__ W2, ushort_t* __restrict__ wfc) {
  __shared__ char lds[131072];
  __shared__ float wmax[8];
  char* P0h = lds;
  char* P0l = lds + 32768;
  char* P1h = lds + 65536;
  char* P1l = lds + 98304;
  const int L = blockIdx.x;
  const float* Wsrc = (L == 0) ? W1 : W2;
  int tid = threadIdx.x;
  int lane = tid & 63;
  int wv = tid >> 6;
  int R0 = (wv >> 1) * 32;
  int C0 = (wv & 1) * 64;

  // ---- scaling ----
  float* f = (float*)lds;
  if (tid < 256) {
    float s = 0.0f;
    if (tid < 128) {
      for (int j = 0; j < FF; j++) s += fabsf(Wsrc[tid * FF + j]);
    } else {
      int c = tid - 128;
      for (int j = 0; j < FF; j++) s += fabsf(Wsrc[j * FF + c]);
    }
    f[tid] = s;
  }
  __syncthreads();
  if (tid == 0) {
    float rm = 0.0f, cm = 0.0f;
    for (int i = 0; i < 128; i++) { rm = fmaxf(rm, f[i]); cm = fmaxf(cm, f[128 + i]); }
    f[256] = 1.0f / sqrtf(rm * cm);
  }
  __syncthreads();
  float inv_s = f[256];
  __syncthreads();

  // ---- init: v0 = W * inv_s. v.R -> P0, v.C -> P1 ----
  {
    int r = tid >> 2, c0 = (tid & 3) * 32;
    #pragma unroll
    for (int mm = 0; mm < 32; mm += 8) {
      bf16x8 hv, lv;
      #pragma unroll
      for (int t = 0; t < 8; t++) {
        float x = Wsrc[r * FF + c0 + mm + t] * inv_s;
        ushort_t h = f2bf(x);
        ushort_t lo = f2bf(x - bf2f(h));
        hv[t] = (short)h; lv[t] = (short)lo;
      }
      *(bf16x8*)(P0h + swz(r, c0 + mm)) = hv;
      *(bf16x8*)(P0l + swz(r, c0 + mm)) = lv;
      #pragma unroll
      for (int t = 0; t < 8; t++) {
        *(ushort_t*)(P1h + swz(c0 + mm + t, r)) = (ushort_t)(unsigned short)hv[t];
        *(ushort_t*)(P1l + swz(c0 + mm + t, r)) = (ushort_t)(unsigned short)lv[t];
      }
    }
  }
  __syncthreads();

  for (int it = 0; it < BJ_MAX; it++) {
    float ca, cb, cc;
    if (it < NWARM) { ca = 3.4445f; cb = -4.7750f; cc = 2.0315f; }
    else            { ca = 1.875f;  cb = -1.25f;   cc = 0.375f; }

    // phase 1: M = v * v^T
    f32x4 m_acc[2][4] = {};
    mm_product(P0h, P0l, P0h, P0l, R0, C0, lane, m_acc);

    // convergence check: max |M - I|
    {
      int cl = lane & 15, rq = (lane >> 4) * 4;
      float lmax = 0.0f;
      #pragma unroll
      for (int i = 0; i < 2; i++)
      #pragma unroll
      for (int j = 0; j < 4; j++)
      #pragma unroll
      for (int t = 0; t < 4; t++) {
        int row = R0 + i * 16 + rq + t;
        int col = C0 + j * 16 + cl;
        float d = m_acc[i][j][t] - ((row == col) ? 1.0f : 0.0f);
        lmax = fmaxf(lmax, fabsf(d));
      }
      #pragma unroll
      for (int off = 32; off; off >>= 1) lmax = fmaxf(lmax, __shfl_xor(lmax, off));
      if (lane == 0) wmax[wv] = lmax;
    }
    __syncthreads();
    {
      float gmax = 0.0f;
      #pragma unroll
      for (int w = 0; w < 8; w++) gmax = fmaxf(gmax, wmax[w]);
      if (gmax < 1e-4f) break;   // v orthonormal to tolerance
    }
    store_C(P0h, P0l, R0, C0, lane, m_acc);   // M symmetric
    __syncthreads();

    // phase 2: M2 = M*M; P = ca*I + cb*M + cc*M2
    f32x4 p_acc[2][4] = {};
    mm_product(P0h, P0l, P0h, P0l, R0, C0, lane, p_acc);
    {
      int cl = lane & 15, rq = (lane >> 4) * 4;
      #pragma unroll
      for (int i = 0; i < 2; i++)
      #pragma unroll
      for (int j = 0; j < 4; j++)
      #pragma unroll
      for (int t = 0; t < 4; t++) {
        int row = R0 + i * 16 + rq + t;
        int col = C0 + j * 16 + cl;
        float pv = cb * m_acc[i][j][t] + cc * p_acc[i][j][t];
        if (row == col) pv += ca;
        p_acc[i][j][t] = pv;
      }
    }
    __syncthreads();
    store_C(P0h, P0l, R0, C0, lane, p_acc);   // P symmetric
    __syncthreads();

    // phase 3: v' = P * v
    f32x4 v_acc[2][4] = {};
    mm_product(P0h, P0l, P1h, P1l, R0, C0, lane, v_acc);
    __syncthreads();
    store_C(P1h, P1l, R0, C0, lane, v_acc);
    store_R(P0h, P0l, R0, C0, lane, v_acc);
    __syncthreads();
  }

  // writeout: row-major v bf16 planes from P0 (unswizzle)
  {
    ushort_t* oh = wfc + L * 32768;
    ushort_t* ol = oh + 16384;
    int r = tid >> 2;
    int q = tid & 3;
    #pragma unroll
    for (int b = 0; b < 4; b++) {
      int c0 = q * 32 + b * 8;
      bf16x8 hv = *(const bf16x8*)(P0h + swz(r, c0));
      bf16x8 lv = *(const bf16x8*)(P0l + swz(r, c0));
      *(bf16x8*)(oh + r * FF + c0) = hv;
      *(bf16x8*)(ol + r * FF + c0) = lv;
    }
  }
}

// ---------------- MFMA GEMM: Out[N][128] = X @ v^T, B-planes from global ----------------
__global__ __launch_bounds__(256) void gemm_mfma(const float* __restrict__ X,
    const ushort_t* __restrict__ wc, float* __restrict__ Out) {
  __shared__ char xlds[32768];
  char* Xh = xlds;
  char* Xl = xlds + 16384;
  int tid = threadIdx.x;
  int row0 = blockIdx.x * 64;

  {
    int r = tid >> 2;
    int q = (tid & 3) * 32;
    int gr = row0 + r;
    #pragma unroll
    for (int b = 0; b < 32; b += 8) {
      bf16x8 hv, lv;
      if (gr < NN) {
        const float* xp = X + gr * FF + q + b;
        #pragma unroll
        for (int t = 0; t < 8; t++) {
          float xv = xp[t];
          ushort_t h = f2bf(xv);
          hv[t] = (short)h;
          lv[t] = (short)f2bf(xv - bf2f(h));
        }
      } else {
        #pragma unroll
        for (int t = 0; t < 8; t++) { hv[t] = 0; lv[t] = 0; }
      }
      *(bf16x8*)(Xh + swz(r, q + b)) = hv;
      *(bf16x8*)(Xl + swz(r, q + b)) = lv;
    }
  }
  __syncthreads();

  int lane = tid & 63, wv = tid >> 6;
  int R0 = (wv & 1) * 32;
  int C0 = (wv >> 1) * 64;
  int rl = lane & 15, kq = (lane >> 4) * 8;
  f32x4 acc[2][4] = {};
  #pragma unroll
  for (int k0 = 0; k0 < 128; k0 += 32) {
    bf16x8 ah[2], al[2];
    #pragma unroll
    for (int i = 0; i < 2; i++) {
      ah[i] = *(const bf16x8*)(Xh + swz(R0 + i * 16 + rl, k0 + kq));
      al[i] = *(const bf16x8*)(Xl + swz(R0 + i * 16 + rl, k0 + kq));
    }
    #pragma unroll
    for (int j = 0; j < 4; j++) {
      const ushort_t* bp = wc + (C0 + j * 16 + rl) * FF + k0 + kq;
      bf16x8 bh = *(const bf16x8*)bp;
      bf16x8 bl = *(const bf16x8*)(bp + 16384);
      #pragma unroll
      for (int i = 0; i < 2; i++) {
        acc[i][j] = __builtin_amdgcn_mfma_f32_16x16x32_bf16(ah[i], bh, acc[i][j], 0, 0, 0);
        acc[i][j] = __builtin_amdgcn_mfma_f32_16x16x32_bf16(ah[i], bl, acc[i][j], 0, 0, 0);
        acc[i][j] = __builtin_amdgcn_mfma_f32_16x16x32_bf16(al[i], bh, acc[i][j], 0, 0, 0);
      }
    }
  }
  int rq = (lane >> 4) * 4;
  #pragma unroll
  for (int i = 0; i < 2; i++)
  #pragma unroll
  for (int j = 0; j < 4; j++) {
    int col = C0 + j * 16 + rl;
    #pragma unroll
    for (int t = 0; t < 4; t++) {
      int node = row0 + R0 + i * 16 + rq + t;
      if (node < NN) Out[node * FF + col] = acc[i][j][t];
    }
  }
}

// ---------------- SpMM + relu (layer 1) ----------------
__global__ __launch_bounds__(256) void spmm_relu(const float* __restrict__ G,
    float* __restrict__ Hout, const float* __restrict__ dinv,
    const int* __restrict__ rowstart, const int* __restrict__ srcl) {
  int g = threadIdx.x >> 5;
  int lane = threadIdx.x & 31;
  int row = blockIdx.x * 8 + g;
  int s = rowstart[row], e = rowstart[row + 1];
  const float4* G4 = (const float4*)G;
  float4 acc = make_float4(0.f, 0.f, 0.f, 0.f);
  for (int p = s; p < e; p++) {
    int r = srcl[p];
    float dr = dinv[r];
    float4 gv = G4[r * 32 + lane];
    acc.x += dr * gv.x; acc.y += dr * gv.y; acc.z += dr * gv.z; acc.w += dr * gv.w;
  }
  float dc = dinv[row];
  float4 o;
  o.x = fmaxf(dc * acc.x, 0.f); o.y = fmaxf(dc * acc.y, 0.f);
  o.z = fmaxf(dc * acc.z, 0.f); o.w = fmaxf(dc * acc.w, 0.f);
  ((float4*)Hout)[row * 32 + lane] = o;
}

// ---------------- fused SpMM2 + head (+log_softmax): 8 rows/block ----------------
__global__ __launch_bounds__(256) void spmm_head(const float* __restrict__ G,
    const float* __restrict__ dinv, const int* __restrict__ rowstart,
    const int* __restrict__ srcl, const float* __restrict__ lw,
    const float* __restrict__ lb, float* __restrict__ out) {
  __shared__ float slw[NOUT * 130];
  __shared__ float slb[64];
  __shared__ float sh[8][128];
  int tid = threadIdx.x;
  for (int i = tid; i < NOUT * 128; i += 256) {
    int r = i >> 7, c = i & 127;
    slw[r * 130 + c] = lw[r * FF + c];
  }
  if (tid < 64) slb[tid] = (tid < NOUT) ? lb[tid] : 0.0f;

  // phase A: spmm + relu for 8 rows -> sh
  {
    int g = tid >> 5, lane32 = tid & 31;
    int row = blockIdx.x * 8 + g;
    int s = rowstart[row], e = rowstart[row + 1];
    const float4* G4 = (const float4*)G;
    float4 acc = make_float4(0.f, 0.f, 0.f, 0.f);
    for (int p = s; p < e; p++) {
      int r = srcl[p];
      float dr = dinv[r];
      float4 gv = G4[r * 32 + lane32];
      acc.x += dr * gv.x; acc.y += dr * gv.y; acc.z += dr * gv.z; acc.w += dr * gv.w;
    }
    float dc = dinv[row];
    float4 o;
    o.x = fmaxf(dc * acc.x, 0.f); o.y = fmaxf(dc * acc.y, 0.f);
    o.z = fmaxf(dc * acc.z, 0.f); o.w = fmaxf(dc * acc.w, 0.f);
    ((float4*)&sh[g][0])[lane32] = o;
  }
  __syncthreads();

  // phase B: 4 waves x 2 rows each: logits + log_softmax
  int lane = tid & 63, w = tid >> 6;
  int ll = (lane < NOUT) ? lane : 0;             // clamp to stay in slw
  const float2* wrow = (const float2*)(slw + ll * 130);
  #pragma unroll
  for (int rr = 0; rr < 2; rr++) {
    int lrow = w * 2 + rr;
    int node = blockIdx.x * 8 + lrow;
    const float2* hrow = (const float2*)&sh[lrow][0];
    float val = slb[lane];
    #pragma unroll 4
    for (int k = 0; k < 64; k++) {
      float2 w2 = wrow[k];
      float2 h2 = hrow[k];
      val += w2.x * h2.x + w2.y * h2.y;
    }
    float m = (lane < NOUT) ? val : -INFINITY;
    for (int off = 32; off; off >>= 1) m = fmaxf(m, __shfl_down(m, off));
    m = __shfl(m, 0);
    float ex = (lane < NOUT) ? expf(val - m) : 0.0f;
    float ssum = ex;
    for (int off = 32; off; off >>= 1) ssum += __shfl_down(ssum, off);
    ssum = __shfl(ssum, 0);
    if (lane < NOUT) out[node * NOUT + lane] = val - m - logf(ssum);
  }
}

extern "C" void kernel_launch(void* const* d_in, const int* in_sizes, int n_in,
                              void* d_out, int out_size, void* d_ws, size_t ws_size,
                              hipStream_t stream) {
  const float* x  = (const float*)d_in[0];
  const float* W1 = (const float*)d_in[1];
  const float* W2 = (const float*)d_in[2];
  const float* lw = (const float*)d_in[3];
  const float* lb = (const float*)d_in[4];
  const int*   ei = (const int*)d_in[5];
  float* out = (float*)d_out;

  float* base = (float*)d_ws;
  float* wb   = base;                 // 65536 floats (spare)
  float* wf   = wb + 65536;           // bf16 planes (2 weights)
  float* degf = wf + 32768;           // NN
  float* dinv = degf + NN;            // NN
  int* cnt      = (int*)(dinv + NN);
  int* rowstart = cnt + NN;           // NN+1 (padded to 12004)
  int* fill     = rowstart + 12004;
  int* srcl     = fill + NN;          // EE
  float* bufA = (float*)(srcl + EE);  // NN*FF
  float* bufB = bufA + NN * FF;       // NN*FF
  ushort_t* wfc = (ushort_t*)wf;

  hipMemsetAsync(degf, 0, NN * sizeof(float), stream);
  hipMemsetAsync(cnt, 0, NN * sizeof(int), stream);
  hipMemsetAsync(fill, 0, NN * sizeof(int), stream);

  build_deg<<<(EE + 255) / 256, 256, 0, stream>>>(ei, degf, cnt);
  scan_dinv_kernel<<<1, 1024, 0, stream>>>(cnt, rowstart, degf, dinv);
  scatter_edges<<<(EE + 255) / 256, 256, 0, stream>>>(ei, rowstart, fill, srcl);
  bjorck_mfma<<<2, 512, 0, stream>>>(W1, W2, wfc);

  gemm_mfma<<<(NN + 63) / 64, 256, 0, stream>>>(x, wfc, bufA);
  spmm_relu<<<NN / 8, 256, 0, stream>>>(bufA, bufB, dinv, rowstart, srcl);
  gemm_mfma<<<(NN + 63) / 64, 256, 0, stream>>>(bufB, wfc + 32768, bufA);
  spmm_head<<<NN / 8, 256, 0, stream>>>(bufA, dinv, rowstart, srcl, lw, lb, out);
}

// Round 6
// 307.783 us; speedup vs baseline: 4.1934x; 1.0184x over previous
//
#include <hip/hip_runtime.h>
#include <math.h>

#define NN 12000
#define EE 384000
#define FF 128
#define NOUT 40
#define BJ_MAX 25
#define NWARM 8
#define EXIT_TOL 3e-3f

typedef __attribute__((ext_vector_type(8))) short bf16x8;
typedef __attribute__((ext_vector_type(4))) short s16x4;
typedef __attribute__((ext_vector_type(4))) float f32x4;
typedef unsigned short ushort_t;

__device__ __forceinline__ ushort_t f2bf(float x) {
  unsigned u = __float_as_uint(x);
  unsigned r = (u + 0x7FFFu + ((u >> 16) & 1u)) >> 16;
  return (ushort_t)r;
}
__device__ __forceinline__ float bf2f(ushort_t h) {
  return __uint_as_float(((unsigned)h) << 16);
}
// swizzled byte offset of element (r, c) in a row-major [*][128] bf16 plane
__device__ __forceinline__ int swz(int r, int c) {
  return ((r << 8) + (c << 1)) ^ ((r & 7) << 4);
}

// ---------------- degree counting ----------------
__global__ __launch_bounds__(256) void build_deg(const int* __restrict__ ei,
    float* __restrict__ degf, int* __restrict__ cnt) {
  int e = blockIdx.x * 256 + threadIdx.x;
  if (e >= EE) return;
  atomicAdd(&degf[ei[e]], 1.0f);
  atomicAdd(&cnt[ei[EE + e]], 1);
}

// ---------------- exclusive scan + fused dinv ----------------
__global__ __launch_bounds__(1024) void scan_dinv_kernel(const int* __restrict__ cnt,
    int* __restrict__ rowstart, const float* __restrict__ degf, float* __restrict__ dinv) {
  __shared__ int sums[1024];
  int tid = threadIdx.x;
  const int CH = 12;
  int base = tid * CH;
  int local[CH];
  int s = 0;
  #pragma unroll
  for (int m = 0; m < CH; m++) {
    int idx = base + m;
    int v = (idx < NN) ? cnt[idx] : 0;
    local[m] = s;
    s += v;
  }
  sums[tid] = s;
  __syncthreads();
  for (int off = 1; off < 1024; off <<= 1) {
    int v = (tid >= off) ? sums[tid - off] : 0;
    __syncthreads();
    sums[tid] += v;
    __syncthreads();
  }
  int excl = (tid > 0) ? sums[tid - 1] : 0;
  #pragma unroll
  for (int m = 0; m < CH; m++) {
    int idx = base + m;
    if (idx < NN) rowstart[idx] = excl + local[m];
  }
  if (tid == 1023) rowstart[NN] = sums[1023];
  for (int i = tid; i < NN; i += 1024) {
    float dv = degf[i];
    dinv[i] = (dv > 0.0f) ? (1.0f / sqrtf(dv)) : 0.0f;
  }
}

// ---------------- scatter edges into CSR ----------------
__global__ __launch_bounds__(256) void scatter_edges(const int* __restrict__ ei,
    const int* __restrict__ rowstart, int* __restrict__ fill, int* __restrict__ srcl) {
  int e = blockIdx.x * 256 + threadIdx.x;
  if (e >= EE) return;
  int r = ei[e], c = ei[EE + e];
  int pos = rowstart[c] + atomicAdd(&fill[c], 1);
  srcl[pos] = r;
}

// ============ MFMA Bjorck (4 waves, 64x64 tiles/wave) ============
// Per-wave 64x64 output tile -> operand duplication 2x2 (vs 2x4 with 8 waves):
// 256 ds_read_b128 per 128^3 matmul instead of 384 — LDS-read-bound floor drops.
__device__ __forceinline__ void mm_product64(const char* Xh, const char* Xl,
    const char* Yh, const char* Yl, int R0, int C0, int lane, f32x4 (&acc)[4][4]) {
  int rl = lane & 15;
  int kq = (lane >> 4) * 8;
  #pragma unroll
  for (int k0 = 0; k0 < 128; k0 += 32) {
    bf16x8 ah[4], al[4];
    #pragma unroll
    for (int i = 0; i < 4; i++) {
      ah[i] = *(const bf16x8*)(Xh + swz(R0 + i * 16 + rl, k0 + kq));
      al[i] = *(const bf16x8*)(Xl + swz(R0 + i * 16 + rl, k0 + kq));
    }
    #pragma unroll
    for (int j = 0; j < 4; j++) {
      bf16x8 bh = *(const bf16x8*)(Yh + swz(C0 + j * 16 + rl, k0 + kq));
      bf16x8 bl = *(const bf16x8*)(Yl + swz(C0 + j * 16 + rl, k0 + kq));
      #pragma unroll
      for (int i = 0; i < 4; i++) {
        acc[i][j] = __builtin_amdgcn_mfma_f32_16x16x32_bf16(ah[i], bh, acc[i][j], 0, 0, 0);
        acc[i][j] = __builtin_amdgcn_mfma_f32_16x16x32_bf16(ah[i], bl, acc[i][j], 0, 0, 0);
        acc[i][j] = __builtin_amdgcn_mfma_f32_16x16x32_bf16(al[i], bh, acc[i][j], 0, 0, 0);
      }
    }
  }
}

// .C-style store (stored-row = output col), b64 writes
__device__ __forceinline__ void store_C64(char* Ch, char* Cl, int R0, int C0,
    int lane, f32x4 (&acc)[4][4]) {
  int cl = lane & 15, rq = (lane >> 4) * 4;
  #pragma unroll
  for (int i = 0; i < 4; i++)
  #pragma unroll
  for (int j = 0; j < 4; j++) {
    int col = C0 + j * 16 + cl;
    int row = R0 + i * 16 + rq;
    s16x4 hv, lv;
    #pragma unroll
    for (int t = 0; t < 4; t++) {
      float x = acc[i][j][t];
      ushort_t h = f2bf(x);
      ushort_t lo = f2bf(x - bf2f(h));
      hv[t] = (short)h; lv[t] = (short)lo;
    }
    *(s16x4*)(Ch + swz(col, row)) = hv;
    *(s16x4*)(Cl + swz(col, row)) = lv;
  }
}

// combined store: .C (b64) + .R (b16 scatter), h/l conversion computed once
__device__ __forceinline__ void store_CR64(char* Ch, char* Cl, char* Rh, char* Rl,
    int R0, int C0, int lane, f32x4 (&acc)[4][4]) {
  int cl = lane & 15, rq = (lane >> 4) * 4;
  #pragma unroll
  for (int i = 0; i < 4; i++)
  #pragma unroll
  for (int j = 0; j < 4; j++) {
    int col = C0 + j * 16 + cl;
    int row = R0 + i * 16 + rq;
    s16x4 hv, lv;
    #pragma unroll
    for (int t = 0; t < 4; t++) {
      float x = acc[i][j][t];
      ushort_t h = f2bf(x);
      ushort_t lo = f2bf(x - bf2f(h));
      hv[t] = (short)h; lv[t] = (short)lo;
    }
    *(s16x4*)(Ch + swz(col, row)) = hv;
    *(s16x4*)(Cl + swz(col, row)) = lv;
    #pragma unroll
    for (int t = 0; t < 4; t++) {
      *(ushort_t*)(Rh + swz(row + t, col)) = (ushort_t)(unsigned short)hv[t];
      *(ushort_t*)(Rl + swz(row + t, col)) = (ushort_t)(unsigned short)lv[t];
    }
  }
}

// One 256-thread workgroup (4 waves) per weight.
// sigma schedule: 8x Muon (3.4445,-4.775,2.0315) lifts sigma_min (~8e-5) into
// the band [0.68,1.20]; one tuned contraction (2.1479,-1.7258,0.5645) maps the
// band to [0.974,1.026] (3-point odd-poly fit; discriminant < 0 -> no real
// roots -> g > 0 on (0,u] -> no singular-value sign flips possible); then
// standard Bjorck until max|M-I| < EXIT_TOL. All iterates are odd polynomials
// of the same W -> same singular vectors; the exit check certifies sigma ~ 1.
__global__ __launch_bounds__(256) void bjorck_mfma(const float* __restrict__ W1,
    const float* __restrict__ W2, ushort_t* __restrict__ wfc) {
  __shared__ char lds[131072];
  __shared__ float wmax[4];
  char* P0h = lds;
  char* P0l = lds + 32768;
  char* P1h = lds + 65536;
  char* P1l = lds + 98304;
  const int L = blockIdx.x;
  const float* Wsrc = (L == 0) ? W1 : W2;
  int tid = threadIdx.x;
  int lane = tid & 63;
  int wv = tid >> 6;
  int R0 = (wv >> 1) * 64;
  int C0 = (wv & 1) * 64;

  // ---- scaling = 1/sqrt(max_row_abs_sum * max_col_abs_sum) ----
  float* f = (float*)lds;
  {
    float s = 0.0f;
    if (tid < 128) {
      for (int j = 0; j < FF; j++) s += fabsf(Wsrc[tid * FF + j]);
    } else {
      int c = tid - 128;
      for (int j = 0; j < FF; j++) s += fabsf(Wsrc[j * FF + c]);
    }
    f[tid] = s;
  }
  __syncthreads();
  if (tid == 0) {
    float rm = 0.0f, cm = 0.0f;
    for (int i = 0; i < 128; i++) { rm = fmaxf(rm, f[i]); cm = fmaxf(cm, f[128 + i]); }
    f[256] = 1.0f / sqrtf(rm * cm);
  }
  __syncthreads();
  float inv_s = f[256];
  __syncthreads();

  // ---- init: v0 = W * inv_s. v.R -> P0, v.C -> P1 ----
  {
    int r = tid >> 1, c0 = (tid & 1) * 64;
    #pragma unroll
    for (int mm = 0; mm < 64; mm += 8) {
      bf16x8 hv, lv;
      #pragma unroll
      for (int t = 0; t < 8; t++) {
        float x = Wsrc[r * FF + c0 + mm + t] * inv_s;
        ushort_t h = f2bf(x);
        ushort_t lo = f2bf(x - bf2f(h));
        hv[t] = (short)h; lv[t] = (short)lo;
      }
      *(bf16x8*)(P0h + swz(r, c0 + mm)) = hv;
      *(bf16x8*)(P0l + swz(r, c0 + mm)) = lv;
      #pragma unroll
      for (int t = 0; t < 8; t++) {
        *(ushort_t*)(P1h + swz(c0 + mm + t, r)) = (ushort_t)(unsigned short)hv[t];
        *(ushort_t*)(P1l + swz(c0 + mm + t, r)) = (ushort_t)(unsigned short)lv[t];
      }
    }
  }
  __syncthreads();

  for (int it = 0; it < BJ_MAX; it++) {
    float ca, cb, cc;
    if (it < NWARM)       { ca = 3.4445f; cb = -4.7750f; cc = 2.0315f; }
    else if (it == NWARM) { ca = 2.1479f; cb = -1.7258f; cc = 0.5645f; }
    else                  { ca = 1.875f;  cb = -1.25f;   cc = 0.375f; }

    // phase 1: M = v * v^T  (A: v.R rows; B: v.R rows, since (v^T).C = v.R)
    f32x4 m_acc[4][4] = {};
    mm_product64(P0h, P0l, P0h, P0l, R0, C0, lane, m_acc);

    // convergence check: max |M - I|
    {
      int cl = lane & 15, rq = (lane >> 4) * 4;
      float lmax = 0.0f;
      #pragma unroll
      for (int i = 0; i < 4; i++)
      #pragma unroll
      for (int j = 0; j < 4; j++)
      #pragma unroll
      for (int t = 0; t < 4; t++) {
        int row = R0 + i * 16 + rq + t;
        int col = C0 + j * 16 + cl;
        float d = m_acc[i][j][t] - ((row == col) ? 1.0f : 0.0f);
        lmax = fmaxf(lmax, fabsf(d));
      }
      #pragma unroll
      for (int off = 32; off; off >>= 1) lmax = fmaxf(lmax, __shfl_xor(lmax, off));
      if (lane == 0) wmax[wv] = lmax;
    }
    __syncthreads();
    {
      float gmax = fmaxf(fmaxf(wmax[0], wmax[1]), fmaxf(wmax[2], wmax[3]));
      if (gmax < EXIT_TOL) break;   // v orthonormal to tolerance
    }
    store_C64(P0h, P0l, R0, C0, lane, m_acc);   // M symmetric: .C store == .R
    __syncthreads();

    // phase 2: M2 = M*M; P = ca*I + cb*M + cc*M2
    f32x4 p_acc[4][4] = {};
    mm_product64(P0h, P0l, P0h, P0l, R0, C0, lane, p_acc);
    {
      int cl = lane & 15, rq = (lane >> 4) * 4;
      #pragma unroll
      for (int i = 0; i < 4; i++)
      #pragma unroll
      for (int j = 0; j < 4; j++)
      #pragma unroll
      for (int t = 0; t < 4; t++) {
        int row = R0 + i * 16 + rq + t;
        int col = C0 + j * 16 + cl;
        float pv = cb * m_acc[i][j][t] + cc * p_acc[i][j][t];
        if (row == col) pv += ca;
        p_acc[i][j][t] = pv;
      }
    }
    __syncthreads();
    store_C64(P0h, P0l, R0, C0, lane, p_acc);   // P symmetric
    __syncthreads();

    // phase 3: v' = P * v  (A: P rows from P0; B: v.C rows from P1)
    f32x4 v_acc[4][4] = {};
    mm_product64(P0h, P0l, P1h, P1l, R0, C0, lane, v_acc);
    __syncthreads();
    store_CR64(P1h, P1l, P0h, P0l, R0, C0, lane, v_acc);  // v'.C -> P1, v'.R -> P0
    __syncthreads();
  }

  // writeout: row-major v bf16 planes from P0 (unswizzle)
  {
    ushort_t* oh = wfc + L * 32768;
    ushort_t* ol = oh + 16384;
    int r = tid >> 1, c0 = (tid & 1) * 64;
    #pragma unroll
    for (int b = 0; b < 64; b += 8) {
      bf16x8 hv = *(const bf16x8*)(P0h + swz(r, c0 + b));
      bf16x8 lv = *(const bf16x8*)(P0l + swz(r, c0 + b));
      *(bf16x8*)(oh + r * FF + c0 + b) = hv;
      *(bf16x8*)(ol + r * FF + c0 + b) = lv;
    }
  }
}

// ---------------- MFMA GEMM: Out[N][128] = X @ v^T, B-planes from global ----------------
__global__ __launch_bounds__(256) void gemm_mfma(const float* __restrict__ X,
    const ushort_t* __restrict__ wc, float* __restrict__ Out) {
  __shared__ char xlds[32768];
  char* Xh = xlds;
  char* Xl = xlds + 16384;
  int tid = threadIdx.x;
  int row0 = blockIdx.x * 64;

  {
    int r = tid >> 2;
    int q = (tid & 3) * 32;
    int gr = row0 + r;
    #pragma unroll
    for (int b = 0; b < 32; b += 8) {
      bf16x8 hv, lv;
      if (gr < NN) {
        const float* xp = X + gr * FF + q + b;
        #pragma unroll
        for (int t = 0; t < 8; t++) {
          float xv = xp[t];
          ushort_t h = f2bf(xv);
          hv[t] = (short)h;
          lv[t] = (short)f2bf(xv - bf2f(h));
        }
      } else {
        #pragma unroll
        for (int t = 0; t < 8; t++) { hv[t] = 0; lv[t] = 0; }
      }
      *(bf16x8*)(Xh + swz(r, q + b)) = hv;
      *(bf16x8*)(Xl + swz(r, q + b)) = lv;
    }
  }
  __syncthreads();

  int lane = tid & 63, wv = tid >> 6;
  int R0 = (wv & 1) * 32;
  int C0 = (wv >> 1) * 64;
  int rl = lane & 15, kq = (lane >> 4) * 8;
  f32x4 acc[2][4] = {};
  #pragma unroll
  for (int k0 = 0; k0 < 128; k0 += 32) {
    bf16x8 ah[2], al[2];
    #pragma unroll
    for (int i = 0; i < 2; i++) {
      ah[i] = *(const bf16x8*)(Xh + swz(R0 + i * 16 + rl, k0 + kq));
      al[i] = *(const bf16x8*)(Xl + swz(R0 + i * 16 + rl, k0 + kq));
    }
    #pragma unroll
    for (int j = 0; j < 4; j++) {
      const ushort_t* bp = wc + (C0 + j * 16 + rl) * FF + k0 + kq;
      bf16x8 bh = *(const bf16x8*)bp;
      bf16x8 bl = *(const bf16x8*)(bp + 16384);
      #pragma unroll
      for (int i = 0; i < 2; i++) {
        acc[i][j] = __builtin_amdgcn_mfma_f32_16x16x32_bf16(ah[i], bh, acc[i][j], 0, 0, 0);
        acc[i][j] = __builtin_amdgcn_mfma_f32_16x16x32_bf16(ah[i], bl, acc[i][j], 0, 0, 0);
        acc[i][j] = __builtin_amdgcn_mfma_f32_16x16x32_bf16(al[i], bh, acc[i][j], 0, 0, 0);
      }
    }
  }
  int rq = (lane >> 4) * 4;
  #pragma unroll
  for (int i = 0; i < 2; i++)
  #pragma unroll
  for (int j = 0; j < 4; j++) {
    int col = C0 + j * 16 + rl;
    #pragma unroll
    for (int t = 0; t < 4; t++) {
      int node = row0 + R0 + i * 16 + rq + t;
      if (node < NN) Out[node * FF + col] = acc[i][j][t];
    }
  }
}

// ---------------- SpMM + relu (layer 1) ----------------
__global__ __launch_bounds__(256) void spmm_relu(const float* __restrict__ G,
    float* __restrict__ Hout, const float* __restrict__ dinv,
    const int* __restrict__ rowstart, const int* __restrict__ srcl) {
  int g = threadIdx.x >> 5;
  int lane = threadIdx.x & 31;
  int row = blockIdx.x * 8 + g;
  int s = rowstart[row], e = rowstart[row + 1];
  const float4* G4 = (const float4*)G;
  float4 acc = make_float4(0.f, 0.f, 0.f, 0.f);
  for (int p = s; p < e; p++) {
    int r = srcl[p];
    float dr = dinv[r];
    float4 gv = G4[r * 32 + lane];
    acc.x += dr * gv.x; acc.y += dr * gv.y; acc.z += dr * gv.z; acc.w += dr * gv.w;
  }
  float dc = dinv[row];
  float4 o;
  o.x = fmaxf(dc * acc.x, 0.f); o.y = fmaxf(dc * acc.y, 0.f);
  o.z = fmaxf(dc * acc.z, 0.f); o.w = fmaxf(dc * acc.w, 0.f);
  ((float4*)Hout)[row * 32 + lane] = o;
}

// ---------------- fused SpMM2 + head (+log_softmax): 8 rows/block ----------------
__global__ __launch_bounds__(256) void spmm_head(const float* __restrict__ G,
    const float* __restrict__ dinv, const int* __restrict__ rowstart,
    const int* __restrict__ srcl, const float* __restrict__ lw,
    const float* __restrict__ lb, float* __restrict__ out) {
  __shared__ float slw[NOUT * 130];
  __shared__ float slb[64];
  __shared__ float sh[8][128];
  int tid = threadIdx.x;
  for (int i = tid; i < NOUT * 128; i += 256) {
    int r = i >> 7, c = i & 127;
    slw[r * 130 + c] = lw[r * FF + c];
  }
  if (tid < 64) slb[tid] = (tid < NOUT) ? lb[tid] : 0.0f;

  // phase A: spmm + relu for 8 rows -> sh
  {
    int g = tid >> 5, lane32 = tid & 31;
    int row = blockIdx.x * 8 + g;
    int s = rowstart[row], e = rowstart[row + 1];
    const float4* G4 = (const float4*)G;
    float4 acc = make_float4(0.f, 0.f, 0.f, 0.f);
    for (int p = s; p < e; p++) {
      int r = srcl[p];
      float dr = dinv[r];
      float4 gv = G4[r * 32 + lane32];
      acc.x += dr * gv.x; acc.y += dr * gv.y; acc.z += dr * gv.z; acc.w += dr * gv.w;
    }
    float dc = dinv[row];
    float4 o;
    o.x = fmaxf(dc * acc.x, 0.f); o.y = fmaxf(dc * acc.y, 0.f);
    o.z = fmaxf(dc * acc.z, 0.f); o.w = fmaxf(dc * acc.w, 0.f);
    ((float4*)&sh[g][0])[lane32] = o;
  }
  __syncthreads();

  // phase B: 4 waves x 2 rows each: logits + log_softmax
  int lane = tid & 63, w = tid >> 6;
  int ll = (lane < NOUT) ? lane : 0;
  const float2* wrow = (const float2*)(slw + ll * 130);
  #pragma unroll
  for (int rr = 0; rr < 2; rr++) {
    int lrow = w * 2 + rr;
    int node = blockIdx.x * 8 + lrow;
    const float2* hrow = (const float2*)&sh[lrow][0];
    float val = slb[lane];
    #pragma unroll 4
    for (int k = 0; k < 64; k++) {
      float2 w2 = wrow[k];
      float2 h2 = hrow[k];
      val += w2.x * h2.x + w2.y * h2.y;
    }
    float m = (lane < NOUT) ? val : -INFINITY;
    for (int off = 32; off; off >>= 1) m = fmaxf(m, __shfl_down(m, off));
    m = __shfl(m, 0);
    float ex = (lane < NOUT) ? expf(val - m) : 0.0f;
    float ssum = ex;
    for (int off = 32; off; off >>= 1) ssum += __shfl_down(ssum, off);
    ssum = __shfl(ssum, 0);
    if (lane < NOUT) out[node * NOUT + lane] = val - m - logf(ssum);
  }
}

extern "C" void kernel_launch(void* const* d_in, const int* in_sizes, int n_in,
                              void* d_out, int out_size, void* d_ws, size_t ws_size,
                              hipStream_t stream) {
  const float* x  = (const float*)d_in[0];
  const float* W1 = (const float*)d_in[1];
  const float* W2 = (const float*)d_in[2];
  const float* lw = (const float*)d_in[3];
  const float* lb = (const float*)d_in[4];
  const int*   ei = (const int*)d_in[5];
  float* out = (float*)d_out;

  float* base = (float*)d_ws;
  float* wf   = base;                  // 32768 floats = bf16 h/l planes, 2 weights
  float* degf = wf + 32768;            // NN (memset region start)
  int* cnt      = (int*)(degf + NN);   // NN (memset)
  int* fill     = cnt + NN;            // NN (memset)
  float* dinv = (float*)(fill + NN);   // NN
  int* rowstart = (int*)(dinv + NN);   // NN+1 (pad to 12004)
  int* srcl     = rowstart + 12004;    // EE
  float* bufA = (float*)(srcl + EE);   // NN*FF
  float* bufB = bufA + NN * FF;        // NN*FF
  ushort_t* wfc = (ushort_t*)wf;

  (void)hipMemsetAsync(degf, 0, 3 * NN * sizeof(float), stream);

  build_deg<<<(EE + 255) / 256, 256, 0, stream>>>(ei, degf, cnt);
  scan_dinv_kernel<<<1, 1024, 0, stream>>>(cnt, rowstart, degf, dinv);
  scatter_edges<<<(EE + 255) / 256, 256, 0, stream>>>(ei, rowstart, fill, srcl);
  bjorck_mfma<<<2, 256, 0, stream>>>(W1, W2, wfc);

  gemm_mfma<<<(NN + 63) / 64, 256, 0, stream>>>(x, wfc, bufA);
  spmm_relu<<<NN / 8, 256, 0, stream>>>(bufA, bufB, dinv, rowstart, srcl);
  gemm_mfma<<<(NN + 63) / 64, 256, 0, stream>>>(bufB, wfc + 32768, bufA);
  spmm_head<<<NN / 8, 256, 0, stream>>>(bufA, dinv, rowstart, srcl, lw, lb, out);
}

// Round 7
// 288.555 us; speedup vs baseline: 4.4728x; 1.0666x over previous
//
#include <hip/hip_runtime.h>
#include <math.h>

#define NN 12000
#define EE 384000
#define FF 128
#define NOUT 40
#define BJ_MAX 25
#define NWARM 8
#define EXIT_TOL 3e-3f

typedef __attribute__((ext_vector_type(8))) short bf16x8;
typedef __attribute__((ext_vector_type(4))) short s16x4;
typedef __attribute__((ext_vector_type(4))) float f32x4;
typedef unsigned short ushort_t;

__device__ __forceinline__ ushort_t f2bf(float x) {
  unsigned u = __float_as_uint(x);
  unsigned r = (u + 0x7FFFu + ((u >> 16) & 1u)) >> 16;
  return (ushort_t)r;
}
__device__ __forceinline__ float bf2f(ushort_t h) {
  return __uint_as_float(((unsigned)h) << 16);
}
// swizzled byte offset of element (r, c) in a row-major [*][128] bf16 plane
__device__ __forceinline__ int swz(int r, int c) {
  return ((r << 8) + (c << 1)) ^ ((r & 7) << 4);
}

// ---------------- degree counting ----------------
__global__ __launch_bounds__(256) void build_deg(const int* __restrict__ ei,
    float* __restrict__ degf, int* __restrict__ cnt) {
  int e = blockIdx.x * 256 + threadIdx.x;
  if (e >= EE) return;
  atomicAdd(&degf[ei[e]], 1.0f);
  atomicAdd(&cnt[ei[EE + e]], 1);
}

// ---------------- exclusive scan + fused dinv ----------------
__global__ __launch_bounds__(1024) void scan_dinv_kernel(const int* __restrict__ cnt,
    int* __restrict__ rowstart, const float* __restrict__ degf, float* __restrict__ dinv) {
  __shared__ int sums[1024];
  int tid = threadIdx.x;
  const int CH = 12;
  int base = tid * CH;
  int local[CH];
  int s = 0;
  #pragma unroll
  for (int m = 0; m < CH; m++) {
    int idx = base + m;
    int v = (idx < NN) ? cnt[idx] : 0;
    local[m] = s;
    s += v;
  }
  sums[tid] = s;
  __syncthreads();
  for (int off = 1; off < 1024; off <<= 1) {
    int v = (tid >= off) ? sums[tid - off] : 0;
    __syncthreads();
    sums[tid] += v;
    __syncthreads();
  }
  int excl = (tid > 0) ? sums[tid - 1] : 0;
  #pragma unroll
  for (int m = 0; m < CH; m++) {
    int idx = base + m;
    if (idx < NN) rowstart[idx] = excl + local[m];
  }
  if (tid == 1023) rowstart[NN] = sums[1023];
  for (int i = tid; i < NN; i += 1024) {
    float dv = degf[i];
    dinv[i] = (dv > 0.0f) ? (1.0f / sqrtf(dv)) : 0.0f;
  }
}

// ---------------- scatter edges into CSR ----------------
__global__ __launch_bounds__(256) void scatter_edges(const int* __restrict__ ei,
    const int* __restrict__ rowstart, int* __restrict__ fill, int* __restrict__ srcl) {
  int e = blockIdx.x * 256 + threadIdx.x;
  if (e >= EE) return;
  int r = ei[e], c = ei[EE + e];
  int pos = rowstart[c] + atomicAdd(&fill[c], 1);
  srcl[pos] = r;
}

// ============ MFMA Bjorck (8 waves, 32x64 tile/wave) ============
// 8 waves = 2 waves/SIMD: latency hiding matters more than read count here
// (round-6 lesson: 4 waves = 1/SIMD regressed 120->129 us despite fewer reads).
__device__ __forceinline__ void mm_product(const char* Xh, const char* Xl,
    const char* Yh, const char* Yl, int R0, int C0, int lane, f32x4 (&acc)[2][4]) {
  int rl = lane & 15;
  int kq = (lane >> 4) * 8;
  #pragma unroll
  for (int k0 = 0; k0 < 128; k0 += 32) {
    bf16x8 ah[2], al[2];
    #pragma unroll
    for (int i = 0; i < 2; i++) {
      ah[i] = *(const bf16x8*)(Xh + swz(R0 + i * 16 + rl, k0 + kq));
      al[i] = *(const bf16x8*)(Xl + swz(R0 + i * 16 + rl, k0 + kq));
    }
    #pragma unroll
    for (int j = 0; j < 4; j++) {
      bf16x8 bh = *(const bf16x8*)(Yh + swz(C0 + j * 16 + rl, k0 + kq));
      bf16x8 bl = *(const bf16x8*)(Yl + swz(C0 + j * 16 + rl, k0 + kq));
      #pragma unroll
      for (int i = 0; i < 2; i++) {
        acc[i][j] = __builtin_amdgcn_mfma_f32_16x16x32_bf16(ah[i], bh, acc[i][j], 0, 0, 0);
        acc[i][j] = __builtin_amdgcn_mfma_f32_16x16x32_bf16(ah[i], bl, acc[i][j], 0, 0, 0);
        acc[i][j] = __builtin_amdgcn_mfma_f32_16x16x32_bf16(al[i], bh, acc[i][j], 0, 0, 0);
      }
    }
  }
}

// .C-style store (stored-row = output col), b64 writes
__device__ __forceinline__ void store_C(char* Ch, char* Cl, int R0, int C0,
    int lane, f32x4 (&acc)[2][4]) {
  int cl = lane & 15, rq = (lane >> 4) * 4;
  #pragma unroll
  for (int i = 0; i < 2; i++)
  #pragma unroll
  for (int j = 0; j < 4; j++) {
    int col = C0 + j * 16 + cl;
    int row = R0 + i * 16 + rq;
    s16x4 hv, lv;
    #pragma unroll
    for (int t = 0; t < 4; t++) {
      float x = acc[i][j][t];
      ushort_t h = f2bf(x);
      ushort_t lo = f2bf(x - bf2f(h));
      hv[t] = (short)h; lv[t] = (short)lo;
    }
    *(s16x4*)(Ch + swz(col, row)) = hv;
    *(s16x4*)(Cl + swz(col, row)) = lv;
  }
}

// combined store: .C (b64) + .R (b16 scatter), h/l conversion computed once
__device__ __forceinline__ void store_CR(char* Ch, char* Cl, char* Rh, char* Rl,
    int R0, int C0, int lane, f32x4 (&acc)[2][4]) {
  int cl = lane & 15, rq = (lane >> 4) * 4;
  #pragma unroll
  for (int i = 0; i < 2; i++)
  #pragma unroll
  for (int j = 0; j < 4; j++) {
    int col = C0 + j * 16 + cl;
    int row = R0 + i * 16 + rq;
    s16x4 hv, lv;
    #pragma unroll
    for (int t = 0; t < 4; t++) {
      float x = acc[i][j][t];
      ushort_t h = f2bf(x);
      ushort_t lo = f2bf(x - bf2f(h));
      hv[t] = (short)h; lv[t] = (short)lo;
    }
    *(s16x4*)(Ch + swz(col, row)) = hv;
    *(s16x4*)(Cl + swz(col, row)) = lv;
    #pragma unroll
    for (int t = 0; t < 4; t++) {
      *(ushort_t*)(Rh + swz(row + t, col)) = (ushort_t)(unsigned short)hv[t];
      *(ushort_t*)(Rl + swz(row + t, col)) = (ushort_t)(unsigned short)lv[t];
    }
  }
}

// One 512-thread workgroup (8 waves) per weight.
// sigma schedule: 8x Muon (3.4445,-4.775,2.0315) lifts sigma_min (~8e-5) into
// [0.68,1.20]; one tuned contraction (2.1479,-1.7258,0.5645) maps the band to
// [0.974,1.026]; then standard Bjorck until max|M-I| < EXIT_TOL. All iterates
// are odd polynomials of the same W -> same singular vectors; the exit check
// certifies sigma ~ 1 so the result matches the reference's converged factor.
__global__ __launch_bounds__(512) void bjorck_mfma(const float* __restrict__ W1,
    const float* __restrict__ W2, ushort_t* __restrict__ wfc) {
  __shared__ char lds[131072];
  __shared__ float wmax[8];
  char* P0h = lds;
  char* P0l = lds + 32768;
  char* P1h = lds + 65536;
  char* P1l = lds + 98304;
  const int L = blockIdx.x;
  const float* Wsrc = (L == 0) ? W1 : W2;
  int tid = threadIdx.x;
  int lane = tid & 63;
  int wv = tid >> 6;
  int R0 = (wv >> 1) * 32;       // 4 row-groups x 32 rows
  int C0 = (wv & 1) * 64;        // 2 col-groups x 64 cols

  // ---- scaling = 1/sqrt(max_row_abs_sum * max_col_abs_sum) ----
  float* f = (float*)lds;
  if (tid < 256) {
    float s = 0.0f;
    if (tid < 128) {
      for (int j = 0; j < FF; j++) s += fabsf(Wsrc[tid * FF + j]);
    } else {
      int c = tid - 128;
      for (int j = 0; j < FF; j++) s += fabsf(Wsrc[j * FF + c]);
    }
    f[tid] = s;
  }
  __syncthreads();
  if (tid == 0) {
    float rm = 0.0f, cm = 0.0f;
    for (int i = 0; i < 128; i++) { rm = fmaxf(rm, f[i]); cm = fmaxf(cm, f[128 + i]); }
    f[256] = 1.0f / sqrtf(rm * cm);
  }
  __syncthreads();
  float inv_s = f[256];
  __syncthreads();

  // ---- init: v0 = W * inv_s. v.R -> P0, v.C -> P1 ----
  {
    int r = tid >> 2, c0 = (tid & 3) * 32;
    #pragma unroll
    for (int mm = 0; mm < 32; mm += 8) {
      bf16x8 hv, lv;
      #pragma unroll
      for (int t = 0; t < 8; t++) {
        float x = Wsrc[r * FF + c0 + mm + t] * inv_s;
        ushort_t h = f2bf(x);
        ushort_t lo = f2bf(x - bf2f(h));
        hv[t] = (short)h; lv[t] = (short)lo;
      }
      *(bf16x8*)(P0h + swz(r, c0 + mm)) = hv;
      *(bf16x8*)(P0l + swz(r, c0 + mm)) = lv;
      #pragma unroll
      for (int t = 0; t < 8; t++) {
        *(ushort_t*)(P1h + swz(c0 + mm + t, r)) = (ushort_t)(unsigned short)hv[t];
        *(ushort_t*)(P1l + swz(c0 + mm + t, r)) = (ushort_t)(unsigned short)lv[t];
      }
    }
  }
  __syncthreads();

  for (int it = 0; it < BJ_MAX; it++) {
    float ca, cb, cc;
    if (it < NWARM)       { ca = 3.4445f; cb = -4.7750f; cc = 2.0315f; }
    else if (it == NWARM) { ca = 2.1479f; cb = -1.7258f; cc = 0.5645f; }
    else                  { ca = 1.875f;  cb = -1.25f;   cc = 0.375f; }

    // phase 1: M = v * v^T  (A: v.R rows; B: v.R rows, since (v^T).C = v.R)
    f32x4 m_acc[2][4] = {};
    mm_product(P0h, P0l, P0h, P0l, R0, C0, lane, m_acc);

    // convergence check: max |M - I|
    {
      int cl = lane & 15, rq = (lane >> 4) * 4;
      float lmax = 0.0f;
      #pragma unroll
      for (int i = 0; i < 2; i++)
      #pragma unroll
      for (int j = 0; j < 4; j++)
      #pragma unroll
      for (int t = 0; t < 4; t++) {
        int row = R0 + i * 16 + rq + t;
        int col = C0 + j * 16 + cl;
        float d = m_acc[i][j][t] - ((row == col) ? 1.0f : 0.0f);
        lmax = fmaxf(lmax, fabsf(d));
      }
      #pragma unroll
      for (int off = 32; off; off >>= 1) lmax = fmaxf(lmax, __shfl_xor(lmax, off));
      if (lane == 0) wmax[wv] = lmax;
    }
    __syncthreads();
    {
      float gmax = 0.0f;
      #pragma unroll
      for (int w = 0; w < 8; w++) gmax = fmaxf(gmax, wmax[w]);
      if (gmax < EXIT_TOL) break;   // v orthonormal to tolerance
    }
    store_C(P0h, P0l, R0, C0, lane, m_acc);   // M symmetric: .C store == .R
    __syncthreads();

    // phase 2: M2 = M*M; P = ca*I + cb*M + cc*M2
    f32x4 p_acc[2][4] = {};
    mm_product(P0h, P0l, P0h, P0l, R0, C0, lane, p_acc);
    {
      int cl = lane & 15, rq = (lane >> 4) * 4;
      #pragma unroll
      for (int i = 0; i < 2; i++)
      #pragma unroll
      for (int j = 0; j < 4; j++)
      #pragma unroll
      for (int t = 0; t < 4; t++) {
        int row = R0 + i * 16 + rq + t;
        int col = C0 + j * 16 + cl;
        float pv = cb * m_acc[i][j][t] + cc * p_acc[i][j][t];
        if (row == col) pv += ca;
        p_acc[i][j][t] = pv;
      }
    }
    __syncthreads();
    store_C(P0h, P0l, R0, C0, lane, p_acc);   // P symmetric
    __syncthreads();

    // phase 3: v' = P * v  (A: P rows from P0; B: v.C rows from P1)
    f32x4 v_acc[2][4] = {};
    mm_product(P0h, P0l, P1h, P1l, R0, C0, lane, v_acc);
    __syncthreads();
    store_CR(P1h, P1l, P0h, P0l, R0, C0, lane, v_acc);  // v'.C -> P1, v'.R -> P0
    __syncthreads();
  }

  // writeout: row-major v bf16 planes from P0 (unswizzle)
  {
    ushort_t* oh = wfc + L * 32768;
    ushort_t* ol = oh + 16384;
    int r = tid >> 2;
    int q = tid & 3;
    #pragma unroll
    for (int b = 0; b < 4; b++) {
      int c0 = q * 32 + b * 8;
      bf16x8 hv = *(const bf16x8*)(P0h + swz(r, c0));
      bf16x8 lv = *(const bf16x8*)(P0l + swz(r, c0));
      *(bf16x8*)(oh + r * FF + c0) = hv;
      *(bf16x8*)(ol + r * FF + c0) = lv;
    }
  }
}

// ---------------- MFMA GEMM: Out[N][128] = X @ v^T, B-planes from global ----------------
__global__ __launch_bounds__(256) void gemm_mfma(const float* __restrict__ X,
    const ushort_t* __restrict__ wc, float* __restrict__ Out) {
  __shared__ char xlds[32768];
  char* Xh = xlds;
  char* Xl = xlds + 16384;
  int tid = threadIdx.x;
  int row0 = blockIdx.x * 64;

  {
    int r = tid >> 2;
    int q = (tid & 3) * 32;
    int gr = row0 + r;
    #pragma unroll
    for (int b = 0; b < 32; b += 8) {
      bf16x8 hv, lv;
      if (gr < NN) {
        const float4* xp4 = (const float4*)(X + gr * FF + q + b);
        float4 v0 = xp4[0];
        float4 v1 = xp4[1];
        float xv[8] = {v0.x, v0.y, v0.z, v0.w, v1.x, v1.y, v1.z, v1.w};
        #pragma unroll
        for (int t = 0; t < 8; t++) {
          ushort_t h = f2bf(xv[t]);
          hv[t] = (short)h;
          lv[t] = (short)f2bf(xv[t] - bf2f(h));
        }
      } else {
        #pragma unroll
        for (int t = 0; t < 8; t++) { hv[t] = 0; lv[t] = 0; }
      }
      *(bf16x8*)(Xh + swz(r, q + b)) = hv;
      *(bf16x8*)(Xl + swz(r, q + b)) = lv;
    }
  }
  __syncthreads();

  int lane = tid & 63, wv = tid >> 6;
  int R0 = (wv & 1) * 32;
  int C0 = (wv >> 1) * 64;
  int rl = lane & 15, kq = (lane >> 4) * 8;
  f32x4 acc[2][4] = {};
  #pragma unroll
  for (int k0 = 0; k0 < 128; k0 += 32) {
    bf16x8 ah[2], al[2];
    #pragma unroll
    for (int i = 0; i < 2; i++) {
      ah[i] = *(const bf16x8*)(Xh + swz(R0 + i * 16 + rl, k0 + kq));
      al[i] = *(const bf16x8*)(Xl + swz(R0 + i * 16 + rl, k0 + kq));
    }
    #pragma unroll
    for (int j = 0; j < 4; j++) {
      const ushort_t* bp = wc + (C0 + j * 16 + rl) * FF + k0 + kq;
      bf16x8 bh = *(const bf16x8*)bp;
      bf16x8 bl = *(const bf16x8*)(bp + 16384);
      #pragma unroll
      for (int i = 0; i < 2; i++) {
        acc[i][j] = __builtin_amdgcn_mfma_f32_16x16x32_bf16(ah[i], bh, acc[i][j], 0, 0, 0);
        acc[i][j] = __builtin_amdgcn_mfma_f32_16x16x32_bf16(ah[i], bl, acc[i][j], 0, 0, 0);
        acc[i][j] = __builtin_amdgcn_mfma_f32_16x16x32_bf16(al[i], bh, acc[i][j], 0, 0, 0);
      }
    }
  }
  int rq = (lane >> 4) * 4;
  #pragma unroll
  for (int i = 0; i < 2; i++)
  #pragma unroll
  for (int j = 0; j < 4; j++) {
    int col = C0 + j * 16 + rl;
    #pragma unroll
    for (int t = 0; t < 4; t++) {
      int node = row0 + R0 + i * 16 + rq + t;
      if (node < NN) Out[node * FF + col] = acc[i][j][t];
    }
  }
}

// ---------------- SpMM + relu (layer 1) ----------------
__global__ __launch_bounds__(256) void spmm_relu(const float* __restrict__ G,
    float* __restrict__ Hout, const float* __restrict__ dinv,
    const int* __restrict__ rowstart, const int* __restrict__ srcl) {
  int g = threadIdx.x >> 5;
  int lane = threadIdx.x & 31;
  int row = blockIdx.x * 8 + g;
  int s = rowstart[row], e = rowstart[row + 1];
  const float4* G4 = (const float4*)G;
  float4 acc = make_float4(0.f, 0.f, 0.f, 0.f);
  for (int p = s; p < e; p++) {
    int r = srcl[p];
    float dr = dinv[r];
    float4 gv = G4[r * 32 + lane];
    acc.x += dr * gv.x; acc.y += dr * gv.y; acc.z += dr * gv.z; acc.w += dr * gv.w;
  }
  float dc = dinv[row];
  float4 o;
  o.x = fmaxf(dc * acc.x, 0.f); o.y = fmaxf(dc * acc.y, 0.f);
  o.z = fmaxf(dc * acc.z, 0.f); o.w = fmaxf(dc * acc.w, 0.f);
  ((float4*)Hout)[row * 32 + lane] = o;
}

// ---------------- fused SpMM2 + head (+log_softmax): 8 rows/block ----------------
__global__ __launch_bounds__(256) void spmm_head(const float* __restrict__ G,
    const float* __restrict__ dinv, const int* __restrict__ rowstart,
    const int* __restrict__ srcl, const float* __restrict__ lw,
    const float* __restrict__ lb, float* __restrict__ out) {
  __shared__ float slw[NOUT * 130];
  __shared__ float slb[64];
  __shared__ float sh[8][128];
  int tid = threadIdx.x;
  for (int i = tid; i < NOUT * 128; i += 256) {
    int r = i >> 7, c = i & 127;
    slw[r * 130 + c] = lw[r * FF + c];
  }
  if (tid < 64) slb[tid] = (tid < NOUT) ? lb[tid] : 0.0f;

  // phase A: spmm + relu for 8 rows -> sh
  {
    int g = tid >> 5, lane32 = tid & 31;
    int row = blockIdx.x * 8 + g;
    int s = rowstart[row], e = rowstart[row + 1];
    const float4* G4 = (const float4*)G;
    float4 acc = make_float4(0.f, 0.f, 0.f, 0.f);
    for (int p = s; p < e; p++) {
      int r = srcl[p];
      float dr = dinv[r];
      float4 gv = G4[r * 32 + lane32];
      acc.x += dr * gv.x; acc.y += dr * gv.y; acc.z += dr * gv.z; acc.w += dr * gv.w;
    }
    float dc = dinv[row];
    float4 o;
    o.x = fmaxf(dc * acc.x, 0.f); o.y = fmaxf(dc * acc.y, 0.f);
    o.z = fmaxf(dc * acc.z, 0.f); o.w = fmaxf(dc * acc.w, 0.f);
    ((float4*)&sh[g][0])[lane32] = o;
  }
  __syncthreads();

  // phase B: 4 waves x 2 rows each: logits + log_softmax
  int lane = tid & 63, w = tid >> 6;
  int ll = (lane < NOUT) ? lane : 0;
  const float2* wrow = (const float2*)(slw + ll * 130);
  #pragma unroll
  for (int rr = 0; rr < 2; rr++) {
    int lrow = w * 2 + rr;
    int node = blockIdx.x * 8 + lrow;
    const float2* hrow = (const float2*)&sh[lrow][0];
    float val = slb[lane];
    #pragma unroll 4
    for (int k = 0; k < 64; k++) {
      float2 w2 = wrow[k];
      float2 h2 = hrow[k];
      val += w2.x * h2.x + w2.y * h2.y;
    }
    float m = (lane < NOUT) ? val : -INFINITY;
    for (int off = 32; off; off >>= 1) m = fmaxf(m, __shfl_down(m, off));
    m = __shfl(m, 0);
    float ex = (lane < NOUT) ? expf(val - m) : 0.0f;
    float ssum = ex;
    for (int off = 32; off; off >>= 1) ssum += __shfl_down(ssum, off);
    ssum = __shfl(ssum, 0);
    if (lane < NOUT) out[node * NOUT + lane] = val - m - logf(ssum);
  }
}

extern "C" void kernel_launch(void* const* d_in, const int* in_sizes, int n_in,
                              void* d_out, int out_size, void* d_ws, size_t ws_size,
                              hipStream_t stream) {
  const float* x  = (const float*)d_in[0];
  const float* W1 = (const float*)d_in[1];
  const float* W2 = (const float*)d_in[2];
  const float* lw = (const float*)d_in[3];
  const float* lb = (const float*)d_in[4];
  const int*   ei = (const int*)d_in[5];
  float* out = (float*)d_out;

  float* base = (float*)d_ws;
  float* wf   = base;                  // 32768 floats = bf16 h/l planes, 2 weights
  float* degf = wf + 32768;            // NN (memset region start)
  int* cnt      = (int*)(degf + NN);   // NN (memset)
  int* fill     = cnt + NN;            // NN (memset)
  float* dinv = (float*)(fill + NN);   // NN
  int* rowstart = (int*)(dinv + NN);   // NN+1 (pad to 12004)
  int* srcl     = rowstart + 12004;    // EE
  float* bufA = (float*)(srcl + EE);   // NN*FF
  float* bufB = bufA + NN * FF;        // NN*FF
  ushort_t* wfc = (ushort_t*)wf;

  (void)hipMemsetAsync(degf, 0, 3 * NN * sizeof(float), stream);

  build_deg<<<(EE + 255) / 256, 256, 0, stream>>>(ei, degf, cnt);
  scan_dinv_kernel<<<1, 1024, 0, stream>>>(cnt, rowstart, degf, dinv);
  scatter_edges<<<(EE + 255) / 256, 256, 0, stream>>>(ei, rowstart, fill, srcl);
  bjorck_mfma<<<2, 512, 0, stream>>>(W1, W2, wfc);

  gemm_mfma<<<(NN + 63) / 64, 256, 0, stream>>>(x, wfc, bufA);
  spmm_relu<<<NN / 8, 256, 0, stream>>>(bufA, bufB, dinv, rowstart, srcl);
  gemm_mfma<<<(NN + 63) / 64, 256, 0, stream>>>(bufB, wfc + 32768, bufA);
  spmm_head<<<NN / 8, 256, 0, stream>>>(bufA, dinv, rowstart, srcl, lw, lb, out);
}

// Round 8
// 234.967 us; speedup vs baseline: 5.4929x; 1.2281x over previous
//
#include <hip/hip_runtime.h>
#include <math.h>

#define NN 12000
#define EE 384000
#define FF 128
#define NOUT 40
#define BJ_MAX 25
#define NWARM 8
#define EXIT_TOL 3e-3f
#define GEMM_BLOCKS ((NN + 63) / 64)

typedef __attribute__((ext_vector_type(8))) short bf16x8;
typedef __attribute__((ext_vector_type(4))) short s16x4;
typedef __attribute__((ext_vector_type(4))) float f32x4;
typedef unsigned short ushort_t;

__device__ __forceinline__ ushort_t f2bf(float x) {
  unsigned u = __float_as_uint(x);
  unsigned r = (u + 0x7FFFu + ((u >> 16) & 1u)) >> 16;
  return (ushort_t)r;
}
__device__ __forceinline__ float bf2f(ushort_t h) {
  return __uint_as_float(((unsigned)h) << 16);
}
// swizzled byte offset of element (r, c) in a row-major [*][128] bf16 plane
__device__ __forceinline__ int swz(int r, int c) {
  return ((r << 8) + (c << 1)) ^ ((r & 7) << 4);
}

// ---------------- exclusive scan + fused dinv ----------------
__global__ __launch_bounds__(1024) void scan_dinv_kernel(const int* __restrict__ cnt,
    int* __restrict__ rowstart, const float* __restrict__ degf, float* __restrict__ dinv) {
  __shared__ int sums[1024];
  int tid = threadIdx.x;
  const int CH = 12;
  int base = tid * CH;
  int local[CH];
  int s = 0;
  #pragma unroll
  for (int m = 0; m < CH; m++) {
    int idx = base + m;
    int v = (idx < NN) ? cnt[idx] : 0;
    local[m] = s;
    s += v;
  }
  sums[tid] = s;
  __syncthreads();
  for (int off = 1; off < 1024; off <<= 1) {
    int v = (tid >= off) ? sums[tid - off] : 0;
    __syncthreads();
    sums[tid] += v;
    __syncthreads();
  }
  int excl = (tid > 0) ? sums[tid - 1] : 0;
  #pragma unroll
  for (int m = 0; m < CH; m++) {
    int idx = base + m;
    if (idx < NN) rowstart[idx] = excl + local[m];
  }
  if (tid == 1023) rowstart[NN] = sums[1023];
  for (int i = tid; i < NN; i += 1024) {
    float dv = degf[i];
    dinv[i] = (dv > 0.0f) ? (1.0f / sqrtf(dv)) : 0.0f;
  }
}

// ============ MFMA Bjorck building blocks (8 waves, 32x64 tile/wave) ============
__device__ __forceinline__ void mm_product(const char* Xh, const char* Xl,
    const char* Yh, const char* Yl, int R0, int C0, int lane, f32x4 (&acc)[2][4]) {
  int rl = lane & 15;
  int kq = (lane >> 4) * 8;
  #pragma unroll
  for (int k0 = 0; k0 < 128; k0 += 32) {
    bf16x8 ah[2], al[2];
    #pragma unroll
    for (int i = 0; i < 2; i++) {
      ah[i] = *(const bf16x8*)(Xh + swz(R0 + i * 16 + rl, k0 + kq));
      al[i] = *(const bf16x8*)(Xl + swz(R0 + i * 16 + rl, k0 + kq));
    }
    #pragma unroll
    for (int j = 0; j < 4; j++) {
      bf16x8 bh = *(const bf16x8*)(Yh + swz(C0 + j * 16 + rl, k0 + kq));
      bf16x8 bl = *(const bf16x8*)(Yl + swz(C0 + j * 16 + rl, k0 + kq));
      #pragma unroll
      for (int i = 0; i < 2; i++) {
        acc[i][j] = __builtin_amdgcn_mfma_f32_16x16x32_bf16(ah[i], bh, acc[i][j], 0, 0, 0);
        acc[i][j] = __builtin_amdgcn_mfma_f32_16x16x32_bf16(ah[i], bl, acc[i][j], 0, 0, 0);
        acc[i][j] = __builtin_amdgcn_mfma_f32_16x16x32_bf16(al[i], bh, acc[i][j], 0, 0, 0);
      }
    }
  }
}

__device__ __forceinline__ void store_C(char* Ch, char* Cl, int R0, int C0,
    int lane, f32x4 (&acc)[2][4]) {
  int cl = lane & 15, rq = (lane >> 4) * 4;
  #pragma unroll
  for (int i = 0; i < 2; i++)
  #pragma unroll
  for (int j = 0; j < 4; j++) {
    int col = C0 + j * 16 + cl;
    int row = R0 + i * 16 + rq;
    s16x4 hv, lv;
    #pragma unroll
    for (int t = 0; t < 4; t++) {
      float x = acc[i][j][t];
      ushort_t h = f2bf(x);
      ushort_t lo = f2bf(x - bf2f(h));
      hv[t] = (short)h; lv[t] = (short)lo;
    }
    *(s16x4*)(Ch + swz(col, row)) = hv;
    *(s16x4*)(Cl + swz(col, row)) = lv;
  }
}

__device__ __forceinline__ void store_CR(char* Ch, char* Cl, char* Rh, char* Rl,
    int R0, int C0, int lane, f32x4 (&acc)[2][4]) {
  int cl = lane & 15, rq = (lane >> 4) * 4;
  #pragma unroll
  for (int i = 0; i < 2; i++)
  #pragma unroll
  for (int j = 0; j < 4; j++) {
    int col = C0 + j * 16 + cl;
    int row = R0 + i * 16 + rq;
    s16x4 hv, lv;
    #pragma unroll
    for (int t = 0; t < 4; t++) {
      float x = acc[i][j][t];
      ushort_t h = f2bf(x);
      ushort_t lo = f2bf(x - bf2f(h));
      hv[t] = (short)h; lv[t] = (short)lo;
    }
    *(s16x4*)(Ch + swz(col, row)) = hv;
    *(s16x4*)(Cl + swz(col, row)) = lv;
    #pragma unroll
    for (int t = 0; t < 4; t++) {
      *(ushort_t*)(Rh + swz(row + t, col)) = (ushort_t)(unsigned short)hv[t];
      *(ushort_t*)(Rl + swz(row + t, col)) = (ushort_t)(unsigned short)lv[t];
    }
  }
}

// ============ Mega-kernel: blocks 0,1 = Bjorck; blocks 2+ = build_deg ============
// Bjorck occupies 2 CUs for ~107us; build_deg's atomics run on the other CUs
// inside the same dispatch window (independent work — no ordering assumed).
__global__ __launch_bounds__(512) void bjorck_deg(const int* __restrict__ ei,
    float* __restrict__ degf, int* __restrict__ cnt,
    const float* __restrict__ W1, const float* __restrict__ W2,
    ushort_t* __restrict__ wfc) {
  if (blockIdx.x >= 2) {
    int e = (blockIdx.x - 2) * 512 + threadIdx.x;
    if (e < EE) {
      atomicAdd(&degf[ei[e]], 1.0f);
      atomicAdd(&cnt[ei[EE + e]], 1);
    }
    return;
  }

  __shared__ char lds[131072];
  __shared__ float wmax[8];
  char* P0h = lds;
  char* P0l = lds + 32768;
  char* P1h = lds + 65536;
  char* P1l = lds + 98304;
  const int L = blockIdx.x;
  const float* Wsrc = (L == 0) ? W1 : W2;
  int tid = threadIdx.x;
  int lane = tid & 63;
  int wv = tid >> 6;
  int R0 = (wv >> 1) * 32;
  int C0 = (wv & 1) * 64;

  // ---- scaling = 1/sqrt(max_row_abs_sum * max_col_abs_sum) ----
  float* f = (float*)lds;
  if (tid < 256) {
    float s = 0.0f;
    if (tid < 128) {
      for (int j = 0; j < FF; j++) s += fabsf(Wsrc[tid * FF + j]);
    } else {
      int c = tid - 128;
      for (int j = 0; j < FF; j++) s += fabsf(Wsrc[j * FF + c]);
    }
    f[tid] = s;
  }
  __syncthreads();
  if (tid == 0) {
    float rm = 0.0f, cm = 0.0f;
    for (int i = 0; i < 128; i++) { rm = fmaxf(rm, f[i]); cm = fmaxf(cm, f[128 + i]); }
    f[256] = 1.0f / sqrtf(rm * cm);
  }
  __syncthreads();
  float inv_s = f[256];
  __syncthreads();

  // ---- init: v0 = W * inv_s. v.R -> P0, v.C -> P1 ----
  {
    int r = tid >> 2, c0 = (tid & 3) * 32;
    #pragma unroll
    for (int mm = 0; mm < 32; mm += 8) {
      bf16x8 hv, lv;
      #pragma unroll
      for (int t = 0; t < 8; t++) {
        float x = Wsrc[r * FF + c0 + mm + t] * inv_s;
        ushort_t h = f2bf(x);
        ushort_t lo = f2bf(x - bf2f(h));
        hv[t] = (short)h; lv[t] = (short)lo;
      }
      *(bf16x8*)(P0h + swz(r, c0 + mm)) = hv;
      *(bf16x8*)(P0l + swz(r, c0 + mm)) = lv;
      #pragma unroll
      for (int t = 0; t < 8; t++) {
        *(ushort_t*)(P1h + swz(c0 + mm + t, r)) = (ushort_t)(unsigned short)hv[t];
        *(ushort_t*)(P1l + swz(c0 + mm + t, r)) = (ushort_t)(unsigned short)lv[t];
      }
    }
  }
  __syncthreads();

  // sigma schedule: 8x Muon warm-up, 1 tuned contraction, then standard Bjorck
  // with convergence exit (checked only once warm-up is past — it provably
  // cannot fire earlier: sigma_min ~ 8e-5 * 3.44^it stays far from band).
  for (int it = 0; it < BJ_MAX; it++) {
    float ca, cb, cc;
    if (it < NWARM)       { ca = 3.4445f; cb = -4.7750f; cc = 2.0315f; }
    else if (it == NWARM) { ca = 2.1479f; cb = -1.7258f; cc = 0.5645f; }
    else                  { ca = 1.875f;  cb = -1.25f;   cc = 0.375f; }

    // phase 1: M = v * v^T
    f32x4 m_acc[2][4] = {};
    mm_product(P0h, P0l, P0h, P0l, R0, C0, lane, m_acc);

    if (it > NWARM) {
      // convergence check: max |M - I|
      int cl = lane & 15, rq = (lane >> 4) * 4;
      float lmax = 0.0f;
      #pragma unroll
      for (int i = 0; i < 2; i++)
      #pragma unroll
      for (int j = 0; j < 4; j++)
      #pragma unroll
      for (int t = 0; t < 4; t++) {
        int row = R0 + i * 16 + rq + t;
        int col = C0 + j * 16 + cl;
        float d = m_acc[i][j][t] - ((row == col) ? 1.0f : 0.0f);
        lmax = fmaxf(lmax, fabsf(d));
      }
      #pragma unroll
      for (int off = 32; off; off >>= 1) lmax = fmaxf(lmax, __shfl_xor(lmax, off));
      if (lane == 0) wmax[wv] = lmax;
      __syncthreads();
      float gmax = 0.0f;
      #pragma unroll
      for (int w = 0; w < 8; w++) gmax = fmaxf(gmax, wmax[w]);
      if (gmax < EXIT_TOL) break;   // v orthonormal to tolerance
    } else {
      __syncthreads();               // mm_product reads P0; store_C writes it
    }
    store_C(P0h, P0l, R0, C0, lane, m_acc);   // M symmetric: .C store == .R
    __syncthreads();

    // phase 2: M2 = M*M; P = ca*I + cb*M + cc*M2
    f32x4 p_acc[2][4] = {};
    mm_product(P0h, P0l, P0h, P0l, R0, C0, lane, p_acc);
    {
      int cl = lane & 15, rq = (lane >> 4) * 4;
      #pragma unroll
      for (int i = 0; i < 2; i++)
      #pragma unroll
      for (int j = 0; j < 4; j++)
      #pragma unroll
      for (int t = 0; t < 4; t++) {
        int row = R0 + i * 16 + rq + t;
        int col = C0 + j * 16 + cl;
        float pv = cb * m_acc[i][j][t] + cc * p_acc[i][j][t];
        if (row == col) pv += ca;
        p_acc[i][j][t] = pv;
      }
    }
    __syncthreads();
    store_C(P0h, P0l, R0, C0, lane, p_acc);   // P symmetric
    __syncthreads();

    // phase 3: v' = P * v
    f32x4 v_acc[2][4] = {};
    mm_product(P0h, P0l, P1h, P1l, R0, C0, lane, v_acc);
    __syncthreads();
    store_CR(P1h, P1l, P0h, P0l, R0, C0, lane, v_acc);  // v'.C -> P1, v'.R -> P0
    __syncthreads();
  }

  // writeout: row-major v bf16 planes from P0 (unswizzle)
  {
    ushort_t* oh = wfc + L * 32768;
    ushort_t* ol = oh + 16384;
    int r = tid >> 2;
    int q = tid & 3;
    #pragma unroll
    for (int b = 0; b < 4; b++) {
      int c0 = q * 32 + b * 8;
      bf16x8 hv = *(const bf16x8*)(P0h + swz(r, c0));
      bf16x8 lv = *(const bf16x8*)(P0l + swz(r, c0));
      *(bf16x8*)(oh + r * FF + c0) = hv;
      *(bf16x8*)(ol + r * FF + c0) = lv;
    }
  }
}

// ============ Fused kernel: blocks 0..187 = gemm1 (X @ W1^T); 188+ = scatter ============
// Both depend only on {scan, bjorck}, mutually independent -> run concurrently.
__global__ __launch_bounds__(256) void scatter_gemm1(const int* __restrict__ ei,
    const int* __restrict__ rowstart, int* __restrict__ fill, int* __restrict__ srcl,
    const float* __restrict__ X, const ushort_t* __restrict__ wc,
    float* __restrict__ Out) {
  if (blockIdx.x >= GEMM_BLOCKS) {
    int e = (blockIdx.x - GEMM_BLOCKS) * 256 + threadIdx.x;
    if (e < EE) {
      int r = ei[e], c = ei[EE + e];
      int pos = rowstart[c] + atomicAdd(&fill[c], 1);
      srcl[pos] = r;
    }
    return;
  }

  __shared__ char xlds[32768];
  char* Xh = xlds;
  char* Xl = xlds + 16384;
  int tid = threadIdx.x;
  int row0 = blockIdx.x * 64;

  {
    int r = tid >> 2;
    int q = (tid & 3) * 32;
    int gr = row0 + r;
    #pragma unroll
    for (int b = 0; b < 32; b += 8) {
      bf16x8 hv, lv;
      if (gr < NN) {
        const float4* xp4 = (const float4*)(X + gr * FF + q + b);
        float4 v0 = xp4[0];
        float4 v1 = xp4[1];
        float xv[8] = {v0.x, v0.y, v0.z, v0.w, v1.x, v1.y, v1.z, v1.w};
        #pragma unroll
        for (int t = 0; t < 8; t++) {
          ushort_t h = f2bf(xv[t]);
          hv[t] = (short)h;
          lv[t] = (short)f2bf(xv[t] - bf2f(h));
        }
      } else {
        #pragma unroll
        for (int t = 0; t < 8; t++) { hv[t] = 0; lv[t] = 0; }
      }
      *(bf16x8*)(Xh + swz(r, q + b)) = hv;
      *(bf16x8*)(Xl + swz(r, q + b)) = lv;
    }
  }
  __syncthreads();

  int lane = tid & 63, wv = tid >> 6;
  int R0 = (wv & 1) * 32;
  int C0 = (wv >> 1) * 64;
  int rl = lane & 15, kq = (lane >> 4) * 8;
  f32x4 acc[2][4] = {};
  #pragma unroll
  for (int k0 = 0; k0 < 128; k0 += 32) {
    bf16x8 ah[2], al[2];
    #pragma unroll
    for (int i = 0; i < 2; i++) {
      ah[i] = *(const bf16x8*)(Xh + swz(R0 + i * 16 + rl, k0 + kq));
      al[i] = *(const bf16x8*)(Xl + swz(R0 + i * 16 + rl, k0 + kq));
    }
    #pragma unroll
    for (int j = 0; j < 4; j++) {
      const ushort_t* bp = wc + (C0 + j * 16 + rl) * FF + k0 + kq;
      bf16x8 bh = *(const bf16x8*)bp;
      bf16x8 bl = *(const bf16x8*)(bp + 16384);
      #pragma unroll
      for (int i = 0; i < 2; i++) {
        acc[i][j] = __builtin_amdgcn_mfma_f32_16x16x32_bf16(ah[i], bh, acc[i][j], 0, 0, 0);
        acc[i][j] = __builtin_amdgcn_mfma_f32_16x16x32_bf16(ah[i], bl, acc[i][j], 0, 0, 0);
        acc[i][j] = __builtin_amdgcn_mfma_f32_16x16x32_bf16(al[i], bh, acc[i][j], 0, 0, 0);
      }
    }
  }
  int rq = (lane >> 4) * 4;
  #pragma unroll
  for (int i = 0; i < 2; i++)
  #pragma unroll
  for (int j = 0; j < 4; j++) {
    int col = C0 + j * 16 + rl;
    #pragma unroll
    for (int t = 0; t < 4; t++) {
      int node = row0 + R0 + i * 16 + rq + t;
      if (node < NN) Out[node * FF + col] = acc[i][j][t];
    }
  }
}

// ---------------- plain MFMA GEMM (layer 2) ----------------
__global__ __launch_bounds__(256) void gemm_mfma(const float* __restrict__ X,
    const ushort_t* __restrict__ wc, float* __restrict__ Out) {
  __shared__ char xlds[32768];
  char* Xh = xlds;
  char* Xl = xlds + 16384;
  int tid = threadIdx.x;
  int row0 = blockIdx.x * 64;

  {
    int r = tid >> 2;
    int q = (tid & 3) * 32;
    int gr = row0 + r;
    #pragma unroll
    for (int b = 0; b < 32; b += 8) {
      bf16x8 hv, lv;
      if (gr < NN) {
        const float4* xp4 = (const float4*)(X + gr * FF + q + b);
        float4 v0 = xp4[0];
        float4 v1 = xp4[1];
        float xv[8] = {v0.x, v0.y, v0.z, v0.w, v1.x, v1.y, v1.z, v1.w};
        #pragma unroll
        for (int t = 0; t < 8; t++) {
          ushort_t h = f2bf(xv[t]);
          hv[t] = (short)h;
          lv[t] = (short)f2bf(xv[t] - bf2f(h));
        }
      } else {
        #pragma unroll
        for (int t = 0; t < 8; t++) { hv[t] = 0; lv[t] = 0; }
      }
      *(bf16x8*)(Xh + swz(r, q + b)) = hv;
      *(bf16x8*)(Xl + swz(r, q + b)) = lv;
    }
  }
  __syncthreads();

  int lane = tid & 63, wv = tid >> 6;
  int R0 = (wv & 1) * 32;
  int C0 = (wv >> 1) * 64;
  int rl = lane & 15, kq = (lane >> 4) * 8;
  f32x4 acc[2][4] = {};
  #pragma unroll
  for (int k0 = 0; k0 < 128; k0 += 32) {
    bf16x8 ah[2], al[2];
    #pragma unroll
    for (int i = 0; i < 2; i++) {
      ah[i] = *(const bf16x8*)(Xh + swz(R0 + i * 16 + rl, k0 + kq));
      al[i] = *(const bf16x8*)(Xl + swz(R0 + i * 16 + rl, k0 + kq));
    }
    #pragma unroll
    for (int j = 0; j < 4; j++) {
      const ushort_t* bp = wc + (C0 + j * 16 + rl) * FF + k0 + kq;
      bf16x8 bh = *(const bf16x8*)bp;
      bf16x8 bl = *(const bf16x8*)(bp + 16384);
      #pragma unroll
      for (int i = 0; i < 2; i++) {
        acc[i][j] = __builtin_amdgcn_mfma_f32_16x16x32_bf16(ah[i], bh, acc[i][j], 0, 0, 0);
        acc[i][j] = __builtin_amdgcn_mfma_f32_16x16x32_bf16(ah[i], bl, acc[i][j], 0, 0, 0);
        acc[i][j] = __builtin_amdgcn_mfma_f32_16x16x32_bf16(al[i], bh, acc[i][j], 0, 0, 0);
      }
    }
  }
  int rq = (lane >> 4) * 4;
  #pragma unroll
  for (int i = 0; i < 2; i++)
  #pragma unroll
  for (int j = 0; j < 4; j++) {
    int col = C0 + j * 16 + rl;
    #pragma unroll
    for (int t = 0; t < 4; t++) {
      int node = row0 + R0 + i * 16 + rq + t;
      if (node < NN) Out[node * FF + col] = acc[i][j][t];
    }
  }
}

// ---------------- SpMM + relu (layer 1), 2-edge unroll ----------------
__global__ __launch_bounds__(256) void spmm_relu(const float* __restrict__ G,
    float* __restrict__ Hout, const float* __restrict__ dinv,
    const int* __restrict__ rowstart, const int* __restrict__ srcl) {
  int g = threadIdx.x >> 5;
  int lane = threadIdx.x & 31;
  int row = blockIdx.x * 8 + g;
  int s = rowstart[row], e = rowstart[row + 1];
  const float4* G4 = (const float4*)G;
  float4 a0 = make_float4(0.f, 0.f, 0.f, 0.f);
  float4 a1 = make_float4(0.f, 0.f, 0.f, 0.f);
  int p = s;
  for (; p + 2 <= e; p += 2) {
    int r0 = srcl[p], r1 = srcl[p + 1];
    float d0 = dinv[r0], d1 = dinv[r1];
    float4 g0 = G4[r0 * 32 + lane];
    float4 g1 = G4[r1 * 32 + lane];
    a0.x += d0 * g0.x; a0.y += d0 * g0.y; a0.z += d0 * g0.z; a0.w += d0 * g0.w;
    a1.x += d1 * g1.x; a1.y += d1 * g1.y; a1.z += d1 * g1.z; a1.w += d1 * g1.w;
  }
  if (p < e) {
    int r0 = srcl[p];
    float d0 = dinv[r0];
    float4 g0 = G4[r0 * 32 + lane];
    a0.x += d0 * g0.x; a0.y += d0 * g0.y; a0.z += d0 * g0.z; a0.w += d0 * g0.w;
  }
  float dc = dinv[row];
  float4 o;
  o.x = fmaxf(dc * (a0.x + a1.x), 0.f); o.y = fmaxf(dc * (a0.y + a1.y), 0.f);
  o.z = fmaxf(dc * (a0.z + a1.z), 0.f); o.w = fmaxf(dc * (a0.w + a1.w), 0.f);
  ((float4*)Hout)[row * 32 + lane] = o;
}

// ---------------- fused SpMM2 + head (+log_softmax): 8 rows/block ----------------
__global__ __launch_bounds__(256) void spmm_head(const float* __restrict__ G,
    const float* __restrict__ dinv, const int* __restrict__ rowstart,
    const int* __restrict__ srcl, const float* __restrict__ lw,
    const float* __restrict__ lb, float* __restrict__ out) {
  __shared__ float slw[NOUT * 130];
  __shared__ float slb[64];
  __shared__ float sh[8][128];
  int tid = threadIdx.x;
  // lw staged via float4 (NOUT*128/4 = 1280 float4s)
  for (int i = tid; i < NOUT * 32; i += 256) {
    int r = i >> 5, c4 = i & 31;
    float4 v = ((const float4*)lw)[r * 32 + c4];
    float* dst = slw + r * 130 + c4 * 4;
    dst[0] = v.x; dst[1] = v.y; dst[2] = v.z; dst[3] = v.w;
  }
  if (tid < 64) slb[tid] = (tid < NOUT) ? lb[tid] : 0.0f;

  // phase A: spmm + relu for 8 rows -> sh (2-edge unroll)
  {
    int g = tid >> 5, lane32 = tid & 31;
    int row = blockIdx.x * 8 + g;
    int s = rowstart[row], e = rowstart[row + 1];
    const float4* G4 = (const float4*)G;
    float4 a0 = make_float4(0.f, 0.f, 0.f, 0.f);
    float4 a1 = make_float4(0.f, 0.f, 0.f, 0.f);
    int p = s;
    for (; p + 2 <= e; p += 2) {
      int r0 = srcl[p], r1 = srcl[p + 1];
      float d0 = dinv[r0], d1 = dinv[r1];
      float4 g0 = G4[r0 * 32 + lane32];
      float4 g1 = G4[r1 * 32 + lane32];
      a0.x += d0 * g0.x; a0.y += d0 * g0.y; a0.z += d0 * g0.z; a0.w += d0 * g0.w;
      a1.x += d1 * g1.x; a1.y += d1 * g1.y; a1.z += d1 * g1.z; a1.w += d1 * g1.w;
    }
    if (p < e) {
      int r0 = srcl[p];
      float d0 = dinv[r0];
      float4 g0 = G4[r0 * 32 + lane32];
      a0.x += d0 * g0.x; a0.y += d0 * g0.y; a0.z += d0 * g0.z; a0.w += d0 * g0.w;
    }
    float dc = dinv[row];
    float4 o;
    o.x = fmaxf(dc * (a0.x + a1.x), 0.f); o.y = fmaxf(dc * (a0.y + a1.y), 0.f);
    o.z = fmaxf(dc * (a0.z + a1.z), 0.f); o.w = fmaxf(dc * (a0.w + a1.w), 0.f);
    ((float4*)&sh[g][0])[lane32] = o;
  }
  __syncthreads();

  // phase B: 4 waves x 2 rows each: logits + log_softmax
  int lane = tid & 63, w = tid >> 6;
  int ll = (lane < NOUT) ? lane : 0;
  const float2* wrow = (const float2*)(slw + ll * 130);
  #pragma unroll
  for (int rr = 0; rr < 2; rr++) {
    int lrow = w * 2 + rr;
    int node = blockIdx.x * 8 + lrow;
    const float2* hrow = (const float2*)&sh[lrow][0];
    float val = slb[lane];
    #pragma unroll 4
    for (int k = 0; k < 64; k++) {
      float2 w2 = wrow[k];
      float2 h2 = hrow[k];
      val += w2.x * h2.x + w2.y * h2.y;
    }
    float m = (lane < NOUT) ? val : -INFINITY;
    for (int off = 32; off; off >>= 1) m = fmaxf(m, __shfl_down(m, off));
    m = __shfl(m, 0);
    float ex = (lane < NOUT) ? expf(val - m) : 0.0f;
    float ssum = ex;
    for (int off = 32; off; off >>= 1) ssum += __shfl_down(ssum, off);
    ssum = __shfl(ssum, 0);
    if (lane < NOUT) out[node * NOUT + lane] = val - m - logf(ssum);
  }
}

extern "C" void kernel_launch(void* const* d_in, const int* in_sizes, int n_in,
                              void* d_out, int out_size, void* d_ws, size_t ws_size,
                              hipStream_t stream) {
  const float* x  = (const float*)d_in[0];
  const float* W1 = (const float*)d_in[1];
  const float* W2 = (const float*)d_in[2];
  const float* lw = (const float*)d_in[3];
  const float* lb = (const float*)d_in[4];
  const int*   ei = (const int*)d_in[5];
  float* out = (float*)d_out;

  float* base = (float*)d_ws;
  float* wf   = base;                  // 32768 floats = bf16 h/l planes, 2 weights
  float* degf = wf + 32768;            // NN (memset region start)
  int* cnt      = (int*)(degf + NN);   // NN (memset)
  int* fill     = cnt + NN;            // NN (memset)
  float* dinv = (float*)(fill + NN);   // NN
  int* rowstart = (int*)(dinv + NN);   // NN+1 (pad to 12004)
  int* srcl     = rowstart + 12004;    // EE
  float* bufA = (float*)(srcl + EE);   // NN*FF
  float* bufB = bufA + NN * FF;        // NN*FF
  ushort_t* wfc = (ushort_t*)wf;

  (void)hipMemsetAsync(degf, 0, 3 * NN * sizeof(float), stream);

  // bjorck (blocks 0,1) + build_deg (blocks 2..751) in one dispatch window
  bjorck_deg<<<2 + (EE + 511) / 512, 512, 0, stream>>>(ei, degf, cnt, W1, W2, wfc);
  scan_dinv_kernel<<<1, 1024, 0, stream>>>(cnt, rowstart, degf, dinv);
  // gemm1 (blocks 0..187) + scatter (blocks 188..1687) concurrently
  scatter_gemm1<<<GEMM_BLOCKS + (EE + 255) / 256, 256, 0, stream>>>(
      ei, rowstart, fill, srcl, x, wfc, bufA);
  spmm_relu<<<NN / 8, 256, 0, stream>>>(bufA, bufB, dinv, rowstart, srcl);
  gemm_mfma<<<(NN + 63) / 64, 256, 0, stream>>>(bufB, wfc + 32768, bufA);
  spmm_head<<<NN / 8, 256, 0, stream>>>(bufA, dinv, rowstart, srcl, lw, lb, out);
}